// Round 2
// baseline (8435.158 us; speedup 1.0000x reference)
//
#include <hip/hip_runtime.h>
#include <float.h>
#include <math.h>

#define N_NODES 50000
#define N_EDGES 500000
#define TT 3
#define RR 4
#define HH 8
#define NHID 128
#define NLAYER 2
#define DIN_ 166
#define MAXT_ 240
#define DKH 16
#define NPB 16

// -------------------- helpers --------------------

__device__ __forceinline__ void atomicMaxFloat(float* addr, float value) {
    // canonicalize -0.0 -> +0.0 so the int-punning order trick is total
    value = (value == 0.f) ? 0.f : value;
    if (value >= 0.f) atomicMax((int*)addr, __float_as_int(value));
    else              atomicMin((unsigned int*)addr, __float_as_uint(value));
}

// -------------------- setup kernels --------------------

// Sinusoid RTE table, computed in f64 to match numpy, cast to f32.
__global__ void k_sin_table(float* __restrict__ tab) {
    int idx = blockIdx.x * blockDim.x + threadIdx.x;
    if (idx >= MAXT_ * 64) return;
    int p = idx / 64, i2 = idx % 64;
    const double c = -9.210340371976184 / 128.0;   // -ln(10000)/NH
    double div = exp((double)(2 * i2) * c);
    double a = (double)p * div;
    const double s128 = 0.08838834764831845;       // 1/sqrt(128)
    tab[p * NHID + 2 * i2]     = (float)(sin(a) * s128);
    tab[p * NHID + 2 * i2 + 1] = (float)(cos(a) * s128);
}

// Bin nodes by type (wave-aggregated atomics: 3 atomics per wave).
__global__ void k_bin(const int* __restrict__ ntype, int* __restrict__ cnt,
                      int* __restrict__ lists) {
    int n = blockIdx.x * 256 + threadIdx.x;
    int t = (n < N_NODES) ? ntype[n] : -1;
    int lane = threadIdx.x & 63;
    #pragma unroll
    for (int tt = 0; tt < TT; ++tt) {
        unsigned long long mask = __ballot(t == tt);
        if (mask) {
            int leader = (int)__ffsll(mask) - 1;
            int base = 0;
            if (lane == leader) base = atomicAdd(&cnt[tt], __popcll(mask));
            base = __shfl(base, leader);
            if (t == tt) {
                int rank = __popcll(mask & ((1ULL << lane) - 1ULL));
                lists[tt * N_NODES + base + rank] = n;
            }
        }
    }
}

__global__ void k_init_amax(float* __restrict__ amax, int n) {
    int i = blockIdx.x * blockDim.x + threadIdx.x;
    if (i < n) amax[i] = -FLT_MAX;
}

// -------------------- node-level linears (type-binned) --------------------

// h0 = tanh(x @ adapt_W[t] + adapt_b[t])
__global__ void k_adapter(const float* __restrict__ x, const int* __restrict__ cnt,
                          const int* __restrict__ lists,
                          const float* __restrict__ W, const float* __restrict__ b,
                          float* __restrict__ h) {
    int t = blockIdx.y;
    int c = cnt[t];
    int i0 = blockIdx.x * NPB;
    if (i0 >= c) return;
    int j = threadIdx.x;
    __shared__ float xs[NPB][DIN_];
    __shared__ int nidx[NPB];
    if (j < NPB) nidx[j] = (i0 + j < c) ? lists[t * N_NODES + i0 + j] : -1;
    __syncthreads();
    int nr[NPB];
    #pragma unroll
    for (int m = 0; m < NPB; ++m) nr[m] = nidx[m];
    #pragma unroll
    for (int m = 0; m < NPB; ++m) {
        int n = nr[m];
        for (int d = j; d < DIN_; d += 128)
            xs[m][d] = (n >= 0) ? x[(size_t)n * DIN_ + d] : 0.f;
    }
    __syncthreads();
    const float* Wt = W + (size_t)t * DIN_ * NHID;
    float bj = b[t * NHID + j];
    float acc[NPB];
    #pragma unroll
    for (int m = 0; m < NPB; ++m) acc[m] = bj;
    for (int d = 0; d < DIN_; ++d) {
        float w = Wt[d * NHID + j];
        #pragma unroll
        for (int m = 0; m < NPB; ++m) acc[m] = fmaf(xs[m][d], w, acc[m]);
    }
    #pragma unroll
    for (int m = 0; m < NPB; ++m) {
        int n = nr[m];
        if (n >= 0) h[(size_t)n * NHID + j] = tanhf(acc[m]);
    }
}

// hk = h@kW[t]+kb[t]; q = h@qW[t]+qb[t]; hv = h@vW[t]+vb[t]
__global__ void k_node_lin(const float* __restrict__ h, const int* __restrict__ cnt,
                           const int* __restrict__ lists,
                           const float* __restrict__ Wk, const float* __restrict__ bk,
                           const float* __restrict__ Wq, const float* __restrict__ bq,
                           const float* __restrict__ Wv, const float* __restrict__ bv,
                           float* __restrict__ hk, float* __restrict__ q,
                           float* __restrict__ hv) {
    int t = blockIdx.y;
    int c = cnt[t];
    int i0 = blockIdx.x * NPB;
    if (i0 >= c) return;
    int j = threadIdx.x;
    __shared__ float hs[NPB][NHID];
    __shared__ int nidx[NPB];
    if (j < NPB) nidx[j] = (i0 + j < c) ? lists[t * N_NODES + i0 + j] : -1;
    __syncthreads();
    int nr[NPB];
    #pragma unroll
    for (int m = 0; m < NPB; ++m) nr[m] = nidx[m];
    #pragma unroll
    for (int m = 0; m < NPB; ++m)
        hs[m][j] = (nr[m] >= 0) ? h[(size_t)nr[m] * NHID + j] : 0.f;
    __syncthreads();
    const float* WkT = Wk + (size_t)t * NHID * NHID;
    const float* WqT = Wq + (size_t)t * NHID * NHID;
    const float* WvT = Wv + (size_t)t * NHID * NHID;
    float ak[NPB], aq[NPB], av[NPB];
    float bkj = bk[t * NHID + j], bqj = bq[t * NHID + j], bvj = bv[t * NHID + j];
    #pragma unroll
    for (int m = 0; m < NPB; ++m) { ak[m] = bkj; aq[m] = bqj; av[m] = bvj; }
    for (int i = 0; i < NHID; ++i) {
        float wk = WkT[i * NHID + j];
        float wq = WqT[i * NHID + j];
        float wv = WvT[i * NHID + j];
        #pragma unroll
        for (int m = 0; m < NPB; ++m) {
            float hi = hs[m][i];
            ak[m] = fmaf(hi, wk, ak[m]);
            aq[m] = fmaf(hi, wq, aq[m]);
            av[m] = fmaf(hi, wv, av[m]);
        }
    }
    #pragma unroll
    for (int m = 0; m < NPB; ++m) {
        int n = nr[m];
        if (n >= 0) {
            hk[(size_t)n * NHID + j] = ak[m];
            q [(size_t)n * NHID + j] = aq[m];
            hv[(size_t)n * NHID + j] = av[m];
        }
    }
}

// trans = gelu(agg)@aW[t]+ab[t]; hout = trans*alpha + hin*(1-alpha)
__global__ void k_out(const float* __restrict__ agg, const float* __restrict__ hin,
                      const int* __restrict__ cnt, const int* __restrict__ lists,
                      const float* __restrict__ aW, const float* __restrict__ ab,
                      const float* __restrict__ skp, float* __restrict__ hout) {
    int t = blockIdx.y;
    int c = cnt[t];
    int i0 = blockIdx.x * NPB;
    if (i0 >= c) return;
    int j = threadIdx.x;
    __shared__ float gs[NPB][NHID];
    __shared__ int nidx[NPB];
    if (j < NPB) nidx[j] = (i0 + j < c) ? lists[t * N_NODES + i0 + j] : -1;
    __syncthreads();
    int nr[NPB];
    #pragma unroll
    for (int m = 0; m < NPB; ++m) nr[m] = nidx[m];
    #pragma unroll
    for (int m = 0; m < NPB; ++m) {
        int n = nr[m];
        float xv = (n >= 0) ? agg[(size_t)n * NHID + j] : 0.f;
        gs[m][j] = 0.5f * xv * (1.f + erff(xv * 0.7071067811865476f));
    }
    __syncthreads();
    const float* Wt = aW + (size_t)t * NHID * NHID;
    float bj = ab[t * NHID + j];
    float acc[NPB];
    #pragma unroll
    for (int m = 0; m < NPB; ++m) acc[m] = bj;
    for (int i = 0; i < NHID; ++i) {
        float w = Wt[i * NHID + j];
        #pragma unroll
        for (int m = 0; m < NPB; ++m) acc[m] = fmaf(gs[m][i], w, acc[m]);
    }
    float alpha = 1.f / (1.f + expf(-skp[t]));
    #pragma unroll
    for (int m = 0; m < NPB; ++m) {
        int n = nr[m];
        if (n >= 0)
            hout[(size_t)n * NHID + j] =
                acc[m] * alpha + hin[(size_t)n * NHID + j] * (1.f - alpha);
    }
}

// -------------------- tiny RTE projections --------------------

// proj = RTE_TAB @ rteW + rteb           [240,128]
__global__ void k_rte_proj(const float* __restrict__ tab, const float* __restrict__ rteW,
                           const float* __restrict__ rteb, float* __restrict__ proj) {
    int p = blockIdx.x;
    int j = threadIdx.x;
    __shared__ float ts[NHID];
    ts[j] = tab[p * NHID + j];
    __syncthreads();
    float acc = rteb[j];
    for (int i = 0; i < NHID; ++i) acc = fmaf(ts[i], rteW[i * NHID + j], acc);
    proj[p * NHID + j] = acc;
}

// RK[p][t] = proj[p] @ kW[t]; RV[p][t] = proj[p] @ vW[t]   [240,3,128]
__global__ void k_rkv(const float* __restrict__ proj, const float* __restrict__ kW,
                      const float* __restrict__ vW, float* __restrict__ RK,
                      float* __restrict__ RV) {
    int p = blockIdx.x, t = blockIdx.y;
    int j = threadIdx.x;
    __shared__ float ps[NHID];
    ps[j] = proj[p * NHID + j];
    __syncthreads();
    const float* Wk = kW + (size_t)t * NHID * NHID;
    const float* Wv = vW + (size_t)t * NHID * NHID;
    float ak = 0.f, av = 0.f;
    for (int i = 0; i < NHID; ++i) {
        float pi = ps[i];
        ak = fmaf(pi, Wk[i * NHID + j], ak);
        av = fmaf(pi, Wv[i * NHID + j], av);
    }
    RK[((size_t)p * TT + t) * NHID + j] = ak;
    RV[((size_t)p * TT + t) * NHID + j] = av;
}

// -------------------- edge passes --------------------

// pass 1: att[e,h] = (k_rel . q[tgt]) * pri / 4 ; segment max via atomics
__global__ __launch_bounds__(256) void k_att(
        const float* __restrict__ hk, const float* __restrict__ q,
        const float* __restrict__ RK,
        const int* __restrict__ src, const int* __restrict__ tgt,
        const int* __restrict__ etype, const int* __restrict__ etime,
        const int* __restrict__ ntype,
        const float* __restrict__ rel_att, const float* __restrict__ rel_pri,
        float* __restrict__ att, float* __restrict__ amax) {
    __shared__ float As[RR * HH * DKH * DKH];   // 32 KB
    int tid = threadIdx.x;
    for (int i = tid; i < RR * HH * DKH * DKH; i += 256) As[i] = rel_att[i];
    __syncthreads();
    int idx = blockIdx.x * 256 + tid;
    if (idx >= N_EDGES * HH) return;
    int e = idx >> 3, h = idx & 7;
    int s = src[e], g = tgt[e];
    int r = etype[e], tm = etime[e];
    int t = ntype[s];
    float kv[DKH];
    const float* hkp = hk + (size_t)s * NHID + h * DKH;
    const float* rkp = RK + ((size_t)tm * TT + t) * NHID + h * DKH;
    #pragma unroll
    for (int d = 0; d < DKH; ++d) kv[d] = hkp[d] + rkp[d];
    const float* qp = q + (size_t)g * NHID + h * DKH;
    const float* A = As + (r * HH + h) * DKH * DKH;
    float acc = 0.f;
    #pragma unroll
    for (int f = 0; f < DKH; ++f) {
        float tmp = 0.f;
        #pragma unroll
        for (int d = 0; d < DKH; ++d) tmp = fmaf(kv[d], A[d * DKH + f], tmp);
        acc = fmaf(tmp, qp[f], acc);
    }
    acc *= rel_pri[r * HH + h] * 0.25f;
    att[idx] = acc;
    atomicMaxFloat(&amax[g * HH + h], acc);
}

// pass 2: den[tgt,h] += exp(att - amax[tgt,h])
__global__ __launch_bounds__(256) void k_den(
        const float* __restrict__ att, const int* __restrict__ tgt,
        const float* __restrict__ amax, float* __restrict__ den) {
    int idx = blockIdx.x * 256 + threadIdx.x;
    if (idx >= N_EDGES * HH) return;
    int e = idx >> 3, h = idx & 7;
    int g = tgt[e];
    float ex = expf(att[idx] - amax[g * HH + h]);
    atomicAdd(&den[g * HH + h], ex);
}

// pass 3: agg[tgt] += w * (v_rel)
__global__ __launch_bounds__(256) void k_agg(
        const float* __restrict__ hv, const float* __restrict__ RV,
        const float* __restrict__ att, const float* __restrict__ amax,
        const float* __restrict__ den,
        const int* __restrict__ src, const int* __restrict__ tgt,
        const int* __restrict__ etype, const int* __restrict__ etime,
        const int* __restrict__ ntype,
        const float* __restrict__ rel_msg, float* __restrict__ agg) {
    __shared__ float Ms[RR * HH * DKH * DKH];   // 32 KB
    int tid = threadIdx.x;
    for (int i = tid; i < RR * HH * DKH * DKH; i += 256) Ms[i] = rel_msg[i];
    __syncthreads();
    int idx = blockIdx.x * 256 + tid;
    if (idx >= N_EDGES * HH) return;
    int e = idx >> 3, h = idx & 7;
    int s = src[e], g = tgt[e];
    int r = etype[e], tm = etime[e];
    int t = ntype[s];
    float w = expf(att[idx] - amax[g * HH + h]) / fmaxf(den[g * HH + h], 1e-9f);
    float vv[DKH];
    const float* hvp = hv + (size_t)s * NHID + h * DKH;
    const float* rvp = RV + ((size_t)tm * TT + t) * NHID + h * DKH;
    #pragma unroll
    for (int d = 0; d < DKH; ++d) vv[d] = hvp[d] + rvp[d];
    const float* M = Ms + (r * HH + h) * DKH * DKH;
    float* aggp = agg + (size_t)g * NHID + h * DKH;
    #pragma unroll
    for (int f = 0; f < DKH; ++f) {
        float tmp = 0.f;
        #pragma unroll
        for (int d = 0; d < DKH; ++d) tmp = fmaf(vv[d], M[d * DKH + f], tmp);
        atomicAdd(&aggp[f], w * tmp);
    }
}

// -------------------- launch --------------------

extern "C" void kernel_launch(void* const* d_in, const int* in_sizes, int n_in,
                              void* d_out, int out_size, void* d_ws, size_t ws_size,
                              hipStream_t stream) {
    const float* node_feature = (const float*)d_in[0];
    const int*   node_type    = (const int*)d_in[1];
    const int*   edge_time    = (const int*)d_in[2];
    const int*   edge_index   = (const int*)d_in[3];
    const int*   edge_type    = (const int*)d_in[4];
    const float* adapt_W = (const float*)d_in[5];
    const float* adapt_b = (const float*)d_in[6];
    const float* kW = (const float*)d_in[7];
    const float* kb = (const float*)d_in[8];
    const float* qW = (const float*)d_in[9];
    const float* qb = (const float*)d_in[10];
    const float* vW = (const float*)d_in[11];
    const float* vb = (const float*)d_in[12];
    const float* aW = (const float*)d_in[13];
    const float* ab = (const float*)d_in[14];
    const float* rel_att = (const float*)d_in[15];
    const float* rel_msg = (const float*)d_in[16];
    const float* rel_pri = (const float*)d_in[17];
    const float* skip = (const float*)d_in[18];
    const float* rteW = (const float*)d_in[19];
    const float* rteb = (const float*)d_in[20];

    const int* src = edge_index;             // edge_index[0][:]
    const int* tgt = edge_index + N_EDGES;   // edge_index[1][:]

    float* ws = (float*)d_ws;
    float* hA   = ws; ws += (size_t)N_NODES * NHID;
    float* hB   = ws; ws += (size_t)N_NODES * NHID;
    float* hk   = ws; ws += (size_t)N_NODES * NHID;
    float* hv   = ws; ws += (size_t)N_NODES * NHID;
    float* qb_  = ws; ws += (size_t)N_NODES * NHID;
    float* agg  = ws; ws += (size_t)N_NODES * NHID;
    float* att  = ws; ws += (size_t)N_EDGES * HH;
    float* amax = ws; ws += (size_t)N_NODES * HH;
    float* den  = ws; ws += (size_t)N_NODES * HH;
    float* tab  = ws; ws += MAXT_ * NHID;
    float* proj = ws; ws += MAXT_ * NHID;
    float* RK   = ws; ws += MAXT_ * TT * NHID;
    float* RV   = ws; ws += MAXT_ * TT * NHID;
    int*   cnt   = (int*)ws; ws += 4;
    int*   lists = (int*)ws; ws += (size_t)TT * N_NODES;

    const int nodeBlocksX = (N_NODES + NPB - 1) / NPB;  // 3125
    dim3 nodeGrid(nodeBlocksX, TT);
    const int edgeBlocks = (N_EDGES * HH + 255) / 256;  // 15625

    hipMemsetAsync(cnt, 0, 4 * sizeof(int), stream);
    k_bin<<<(N_NODES + 255) / 256, 256, 0, stream>>>(node_type, cnt, lists);
    k_sin_table<<<(MAXT_ * 64 + 255) / 256, 256, 0, stream>>>(tab);
    k_adapter<<<nodeGrid, 128, 0, stream>>>(node_feature, cnt, lists, adapt_W, adapt_b, hA);

    for (int l = 0; l < NLAYER; ++l) {
        const float* hin = (l == 0) ? hA : hB;
        float* hout = (l == 0) ? hB : (float*)d_out;
        const float* kW_l = kW + (size_t)l * TT * NHID * NHID;
        const float* kb_l = kb + (size_t)l * TT * NHID;
        const float* qW_l = qW + (size_t)l * TT * NHID * NHID;
        const float* qb_l = qb + (size_t)l * TT * NHID;
        const float* vW_l = vW + (size_t)l * TT * NHID * NHID;
        const float* vb_l = vb + (size_t)l * TT * NHID;
        const float* aW_l = aW + (size_t)l * TT * NHID * NHID;
        const float* ab_l = ab + (size_t)l * TT * NHID;
        const float* ratt_l = rel_att + (size_t)l * RR * HH * DKH * DKH;
        const float* rmsg_l = rel_msg + (size_t)l * RR * HH * DKH * DKH;
        const float* rpri_l = rel_pri + (size_t)l * RR * HH;
        const float* skip_l = skip + (size_t)l * TT;
        const float* rteW_l = rteW + (size_t)l * NHID * NHID;
        const float* rteb_l = rteb + (size_t)l * NHID;

        k_rte_proj<<<MAXT_, 128, 0, stream>>>(tab, rteW_l, rteb_l, proj);
        dim3 rkvGrid(MAXT_, TT);
        k_rkv<<<rkvGrid, 128, 0, stream>>>(proj, kW_l, vW_l, RK, RV);
        k_node_lin<<<nodeGrid, 128, 0, stream>>>(hin, cnt, lists,
                                                 kW_l, kb_l, qW_l, qb_l, vW_l, vb_l,
                                                 hk, qb_, hv);
        k_init_amax<<<(N_NODES * HH + 255) / 256, 256, 0, stream>>>(amax, N_NODES * HH);
        hipMemsetAsync(den, 0, (size_t)N_NODES * HH * sizeof(float), stream);
        hipMemsetAsync(agg, 0, (size_t)N_NODES * NHID * sizeof(float), stream);

        k_att<<<edgeBlocks, 256, 0, stream>>>(hk, qb_, RK, src, tgt, edge_type, edge_time,
                                              node_type, ratt_l, rpri_l, att, amax);
        k_den<<<edgeBlocks, 256, 0, stream>>>(att, tgt, amax, den);
        k_agg<<<edgeBlocks, 256, 0, stream>>>(hv, RV, att, amax, den, src, tgt,
                                              edge_type, edge_time, node_type, rmsg_l, agg);
        k_out<<<nodeGrid, 128, 0, stream>>>(agg, hin, cnt, lists, aW_l, ab_l, skip_l, hout);
    }
}

// Round 4
// 2396.358 us; speedup vs baseline: 3.5200x; 3.5200x over previous
//
#include <hip/hip_runtime.h>
#include <float.h>
#include <math.h>

#define N_NODES 50000
#define N_EDGES 500000
#define TT 3
#define RR 4
#define HH 8
#define NHID 128
#define NLAYER 2
#define DIN_ 166
#define MAXT_ 240
#define DKH 16
#define NPB 16

// -------------------- setup kernels --------------------

// Sinusoid RTE table, computed in f64 to match numpy, cast to f32.
__global__ void k_sin_table(float* __restrict__ tab) {
    int idx = blockIdx.x * blockDim.x + threadIdx.x;
    if (idx >= MAXT_ * 64) return;
    int p = idx / 64, i2 = idx % 64;
    const double c = -9.210340371976184 / 128.0;   // -ln(10000)/NH
    double div = exp((double)(2 * i2) * c);
    double a = (double)p * div;
    const double s128 = 0.08838834764831845;       // 1/sqrt(128)
    tab[p * NHID + 2 * i2]     = (float)(sin(a) * s128);
    tab[p * NHID + 2 * i2 + 1] = (float)(cos(a) * s128);
}

// Bin nodes by type (wave-aggregated atomics: 3 atomics per wave).
__global__ void k_bin(const int* __restrict__ ntype, int* __restrict__ cnt,
                      int* __restrict__ lists) {
    int n = blockIdx.x * 256 + threadIdx.x;
    int t = (n < N_NODES) ? ntype[n] : -1;
    int lane = threadIdx.x & 63;
    #pragma unroll
    for (int tt = 0; tt < TT; ++tt) {
        unsigned long long mask = __ballot(t == tt);
        if (mask) {
            int leader = (int)__ffsll(mask) - 1;
            int base = 0;
            if (lane == leader) base = atomicAdd(&cnt[tt], __popcll(mask));
            base = __shfl(base, leader);
            if (t == tt) {
                int rank = __popcll(mask & ((1ULL << lane) - 1ULL));
                lists[tt * N_NODES + base + rank] = n;
            }
        }
    }
}

// -------------------- CSR build (once; edge_index constant across layers) ---

__global__ void k_deg(const int* __restrict__ tgt, int* __restrict__ deg) {
    int e = blockIdx.x * 256 + threadIdx.x;
    if (e < N_EDGES) atomicAdd(&deg[tgt[e]], 1);
}

// single-block exclusive scan: rowptr[0]=0, rowptr[i+1]=sum deg[0..i]
__global__ void k_scan(const int* __restrict__ deg, int* __restrict__ rowptr) {
    __shared__ int wsum[16];
    __shared__ int carry_s;
    int tid = threadIdx.x;           // 1024
    int lane = tid & 63, wid = tid >> 6;
    if (tid == 0) { carry_s = 0; rowptr[0] = 0; }
    __syncthreads();
    for (int base = 0; base < N_NODES; base += 1024) {
        int idx = base + tid;
        int x = (idx < N_NODES) ? deg[idx] : 0;
        #pragma unroll
        for (int off = 1; off < 64; off <<= 1) {
            int y = __shfl_up(x, off, 64);
            if (lane >= off) x += y;
        }
        if (lane == 63) wsum[wid] = x;
        __syncthreads();
        if (wid == 0) {
            int w = (lane < 16) ? wsum[lane] : 0;
            #pragma unroll
            for (int off = 1; off < 16; off <<= 1) {
                int y = __shfl_up(w, off, 64);
                if (lane >= off) w += y;
            }
            if (lane < 16) wsum[lane] = w;
        }
        __syncthreads();
        int waveoff = (wid > 0) ? wsum[wid - 1] : 0;
        int incl = carry_s + waveoff + x;
        if (idx < N_NODES) rowptr[idx + 1] = incl;
        __syncthreads();
        if (tid == 1023) carry_s = incl;
        __syncthreads();
    }
}

__global__ void k_fill(const int* __restrict__ tgt, int* __restrict__ cursor,
                       int* __restrict__ elist) {
    int e = blockIdx.x * 256 + threadIdx.x;
    if (e >= N_EDGES) return;
    int g = tgt[e];
    int p = atomicAdd(&cursor[g], 1);
    elist[p] = e;
}

// -------------------- node-level linears (type-binned) --------------------

__global__ void k_adapter(const float* __restrict__ x, const int* __restrict__ cnt,
                          const int* __restrict__ lists,
                          const float* __restrict__ W, const float* __restrict__ b,
                          float* __restrict__ h) {
    int t = blockIdx.y;
    int c = cnt[t];
    int i0 = blockIdx.x * NPB;
    if (i0 >= c) return;
    int j = threadIdx.x;
    __shared__ float xs[NPB][DIN_];
    __shared__ int nidx[NPB];
    if (j < NPB) nidx[j] = (i0 + j < c) ? lists[t * N_NODES + i0 + j] : -1;
    __syncthreads();
    int nr[NPB];
    #pragma unroll
    for (int m = 0; m < NPB; ++m) nr[m] = nidx[m];
    #pragma unroll
    for (int m = 0; m < NPB; ++m) {
        int n = nr[m];
        for (int d = j; d < DIN_; d += 128)
            xs[m][d] = (n >= 0) ? x[(size_t)n * DIN_ + d] : 0.f;
    }
    __syncthreads();
    const float* Wt = W + (size_t)t * DIN_ * NHID;
    float bj = b[t * NHID + j];
    float acc[NPB];
    #pragma unroll
    for (int m = 0; m < NPB; ++m) acc[m] = bj;
    for (int d = 0; d < DIN_; ++d) {
        float w = Wt[d * NHID + j];
        #pragma unroll
        for (int m = 0; m < NPB; ++m) acc[m] = fmaf(xs[m][d], w, acc[m]);
    }
    #pragma unroll
    for (int m = 0; m < NPB; ++m) {
        int n = nr[m];
        if (n >= 0) h[(size_t)n * NHID + j] = tanhf(acc[m]);
    }
}

__global__ void k_node_lin(const float* __restrict__ h, const int* __restrict__ cnt,
                           const int* __restrict__ lists,
                           const float* __restrict__ Wk, const float* __restrict__ bk,
                           const float* __restrict__ Wq, const float* __restrict__ bq,
                           const float* __restrict__ Wv, const float* __restrict__ bv,
                           float* __restrict__ hk, float* __restrict__ q,
                           float* __restrict__ hv) {
    int t = blockIdx.y;
    int c = cnt[t];
    int i0 = blockIdx.x * NPB;
    if (i0 >= c) return;
    int j = threadIdx.x;
    __shared__ float hs[NPB][NHID];
    __shared__ int nidx[NPB];
    if (j < NPB) nidx[j] = (i0 + j < c) ? lists[t * N_NODES + i0 + j] : -1;
    __syncthreads();
    int nr[NPB];
    #pragma unroll
    for (int m = 0; m < NPB; ++m) nr[m] = nidx[m];
    #pragma unroll
    for (int m = 0; m < NPB; ++m)
        hs[m][j] = (nr[m] >= 0) ? h[(size_t)nr[m] * NHID + j] : 0.f;
    __syncthreads();
    const float* WkT = Wk + (size_t)t * NHID * NHID;
    const float* WqT = Wq + (size_t)t * NHID * NHID;
    const float* WvT = Wv + (size_t)t * NHID * NHID;
    float ak[NPB], aq[NPB], av[NPB];
    float bkj = bk[t * NHID + j], bqj = bq[t * NHID + j], bvj = bv[t * NHID + j];
    #pragma unroll
    for (int m = 0; m < NPB; ++m) { ak[m] = bkj; aq[m] = bqj; av[m] = bvj; }
    for (int i = 0; i < NHID; ++i) {
        float wk = WkT[i * NHID + j];
        float wq = WqT[i * NHID + j];
        float wv = WvT[i * NHID + j];
        #pragma unroll
        for (int m = 0; m < NPB; ++m) {
            float hi = hs[m][i];
            ak[m] = fmaf(hi, wk, ak[m]);
            aq[m] = fmaf(hi, wq, aq[m]);
            av[m] = fmaf(hi, wv, av[m]);
        }
    }
    #pragma unroll
    for (int m = 0; m < NPB; ++m) {
        int n = nr[m];
        if (n >= 0) {
            hk[(size_t)n * NHID + j] = ak[m];
            q [(size_t)n * NHID + j] = aq[m];
            hv[(size_t)n * NHID + j] = av[m];
        }
    }
}

__global__ void k_out(const float* __restrict__ agg, const float* __restrict__ hin,
                      const int* __restrict__ cnt, const int* __restrict__ lists,
                      const float* __restrict__ aW, const float* __restrict__ ab,
                      const float* __restrict__ skp, float* __restrict__ hout) {
    int t = blockIdx.y;
    int c = cnt[t];
    int i0 = blockIdx.x * NPB;
    if (i0 >= c) return;
    int j = threadIdx.x;
    __shared__ float gs[NPB][NHID];
    __shared__ int nidx[NPB];
    if (j < NPB) nidx[j] = (i0 + j < c) ? lists[t * N_NODES + i0 + j] : -1;
    __syncthreads();
    int nr[NPB];
    #pragma unroll
    for (int m = 0; m < NPB; ++m) nr[m] = nidx[m];
    #pragma unroll
    for (int m = 0; m < NPB; ++m) {
        int n = nr[m];
        float xv = (n >= 0) ? agg[(size_t)n * NHID + j] : 0.f;
        gs[m][j] = 0.5f * xv * (1.f + erff(xv * 0.7071067811865476f));
    }
    __syncthreads();
    const float* Wt = aW + (size_t)t * NHID * NHID;
    float bj = ab[t * NHID + j];
    float acc[NPB];
    #pragma unroll
    for (int m = 0; m < NPB; ++m) acc[m] = bj;
    for (int i = 0; i < NHID; ++i) {
        float w = Wt[i * NHID + j];
        #pragma unroll
        for (int m = 0; m < NPB; ++m) acc[m] = fmaf(gs[m][i], w, acc[m]);
    }
    float alpha = 1.f / (1.f + expf(-skp[t]));
    #pragma unroll
    for (int m = 0; m < NPB; ++m) {
        int n = nr[m];
        if (n >= 0)
            hout[(size_t)n * NHID + j] =
                acc[m] * alpha + hin[(size_t)n * NHID + j] * (1.f - alpha);
    }
}

// -------------------- tiny RTE projections --------------------

__global__ void k_rte_proj(const float* __restrict__ tab, const float* __restrict__ rteW,
                           const float* __restrict__ rteb, float* __restrict__ proj) {
    int p = blockIdx.x;
    int j = threadIdx.x;
    __shared__ float ts[NHID];
    ts[j] = tab[p * NHID + j];
    __syncthreads();
    float acc = rteb[j];
    for (int i = 0; i < NHID; ++i) acc = fmaf(ts[i], rteW[i * NHID + j], acc);
    proj[p * NHID + j] = acc;
}

__global__ void k_rkv(const float* __restrict__ proj, const float* __restrict__ kW,
                      const float* __restrict__ vW, float* __restrict__ RK,
                      float* __restrict__ RV) {
    int p = blockIdx.x, t = blockIdx.y;
    int j = threadIdx.x;
    __shared__ float ps[NHID];
    ps[j] = proj[p * NHID + j];
    __syncthreads();
    const float* Wk = kW + (size_t)t * NHID * NHID;
    const float* Wv = vW + (size_t)t * NHID * NHID;
    float ak = 0.f, av = 0.f;
    for (int i = 0; i < NHID; ++i) {
        float pi = ps[i];
        ak = fmaf(pi, Wk[i * NHID + j], ak);
        av = fmaf(pi, Wv[i * NHID + j], av);
    }
    RK[((size_t)p * TT + t) * NHID + j] = ak;
    RV[((size_t)p * TT + t) * NHID + j] = av;
}

// -------------------- edge pass 1: attention scores --------------------

// att[e,h] = (q[tgt] . A_rh^T(hk[src]+RK)) * pri / 4  — plain coalesced write.
// LDS swizzle: off ^ rh → at fixed (d,f) the 32 distinct rh land in 32 banks.
__global__ __launch_bounds__(256) void k_att(
        const float* __restrict__ hk, const float* __restrict__ q,
        const float* __restrict__ RK,
        const int* __restrict__ src, const int* __restrict__ tgt,
        const int* __restrict__ etype, const int* __restrict__ etime,
        const int* __restrict__ ntype,
        const float* __restrict__ rel_att, const float* __restrict__ rel_pri,
        float* __restrict__ att) {
    __shared__ float As[RR * HH * 256];   // 32 KB, XOR-swizzled
    int tid = threadIdx.x;
    for (int i = tid; i < RR * HH * 256; i += 256) {
        int rh = i >> 8, off = i & 255;
        As[(rh << 8) | (off ^ rh)] = rel_att[i];
    }
    __syncthreads();
    int idx = blockIdx.x * 256 + tid;
    if (idx >= N_EDGES * HH) return;
    int e = idx >> 3, h = idx & 7;
    int s = src[e], g = tgt[e];
    int r = etype[e], tm = etime[e];
    int t = ntype[s];
    float kv[DKH];
    const float* hkp = hk + (size_t)s * NHID + h * DKH;
    const float* rkp = RK + ((size_t)tm * TT + t) * NHID + h * DKH;
    #pragma unroll
    for (int d = 0; d < DKH; ++d) kv[d] = hkp[d] + rkp[d];
    const float* qp = q + (size_t)g * NHID + h * DKH;
    int rh = r * HH + h;
    const float* A = As + (rh << 8);
    float acc = 0.f;
    #pragma unroll
    for (int f = 0; f < DKH; ++f) {
        float tmp = 0.f;
        #pragma unroll
        for (int d = 0; d < DKH; ++d) tmp = fmaf(kv[d], A[(d * 16 + f) ^ rh], tmp);
        acc = fmaf(tmp, qp[f], acc);
    }
    acc *= rel_pri[rh] * 0.25f;
    att[idx] = acc;
}

// -------------------- edge pass 2: CSR softmax + aggregate (no atomics) ----

// one block of 128 per target node; thread j = h*16+f owns output dim j.
__global__ __launch_bounds__(128) void k_csr(
        const float* __restrict__ hv, const float* __restrict__ RV,
        const float* __restrict__ att,
        const int* __restrict__ rowptr, const int* __restrict__ elist,
        const int* __restrict__ src, const int* __restrict__ etype,
        const int* __restrict__ etime, const int* __restrict__ ntype,
        const float* __restrict__ rel_msg, float* __restrict__ agg) {
    int n = blockIdx.x;
    int tid = threadIdx.x;
    int h = tid >> 4, f = tid & 15;
    __shared__ float Ms[RR * HH * 256];   // 32 KB; ^((rh&1)<<4) → 2-way max (free)
    for (int i = tid; i < RR * HH * 256; i += 128) {
        int rh = i >> 8, off = i & 255;
        Ms[(rh << 8) | (off ^ ((rh & 1) << 4))] = rel_msg[i];
    }
    int beg = rowptr[n], end = rowptr[n + 1];

    // Phase A: online (max, sumexp) for head h; 16 lanes per head cooperate.
    float m = -FLT_MAX, ssum = 0.f;
    for (int k = beg + f; k < end; k += 16) {
        int e = elist[k];
        float a = att[(size_t)e * HH + h];
        if (a > m) { ssum *= expf(m - a); m = a; }
        ssum += expf(a - m);
    }
    #pragma unroll
    for (int mask = 1; mask <= 8; mask <<= 1) {
        float om = __shfl_xor(m, mask, 64);
        float os = __shfl_xor(ssum, mask, 64);
        float nm = fmaxf(m, om);
        ssum = ssum * expf(m - nm) + os * expf(om - nm);
        m = nm;
    }
    float rden = 1.f / fmaxf(ssum, 1e-9f);
    __syncthreads();   // Ms ready

    // Phase B: accumulate agg[n][h*16+f] over edges.
    float acc = 0.f;
    const float* Mbase = Ms;
    int lanebase = tid & 48;
    int swz = (h & 1) << 4;
    for (int k = beg; k < end; ++k) {
        int e = elist[k];
        int s = src[e], r = etype[e], tm = etime[e];
        int t = ntype[s];
        // vv[tid]: wave 0 holds dims 0..63, wave 1 dims 64..127
        float vvt = hv[(size_t)s * NHID + tid] + RV[((size_t)tm * TT + t) * NHID + tid];
        float w = expf(att[(size_t)e * HH + h] - m) * rden;
        const float* M = Mbase + ((r * HH + h) << 8);
        float tmp = 0.f;
        #pragma unroll
        for (int d = 0; d < DKH; ++d) {
            float vd = __shfl(vvt, lanebase + d, 64);
            tmp = fmaf(vd, M[(d * 16 + f) ^ swz], tmp);
        }
        acc = fmaf(w, tmp, acc);
    }
    agg[(size_t)n * NHID + tid] = acc;
}

// -------------------- launch --------------------

extern "C" void kernel_launch(void* const* d_in, const int* in_sizes, int n_in,
                              void* d_out, int out_size, void* d_ws, size_t ws_size,
                              hipStream_t stream) {
    const float* node_feature = (const float*)d_in[0];
    const int*   node_type    = (const int*)d_in[1];
    const int*   edge_time    = (const int*)d_in[2];
    const int*   edge_index   = (const int*)d_in[3];
    const int*   edge_type    = (const int*)d_in[4];
    const float* adapt_W = (const float*)d_in[5];
    const float* adapt_b = (const float*)d_in[6];
    const float* kW = (const float*)d_in[7];
    const float* kb = (const float*)d_in[8];
    const float* qW = (const float*)d_in[9];
    const float* qb = (const float*)d_in[10];
    const float* vW = (const float*)d_in[11];
    const float* vb = (const float*)d_in[12];
    const float* aW = (const float*)d_in[13];
    const float* ab = (const float*)d_in[14];
    const float* rel_att = (const float*)d_in[15];
    const float* rel_msg = (const float*)d_in[16];
    const float* rel_pri = (const float*)d_in[17];
    const float* skip = (const float*)d_in[18];
    const float* rteW = (const float*)d_in[19];
    const float* rteb = (const float*)d_in[20];

    const int* src = edge_index;             // edge_index[0][:]
    const int* tgt = edge_index + N_EDGES;   // edge_index[1][:]

    float* ws = (float*)d_ws;
    float* hA   = ws; ws += (size_t)N_NODES * NHID;
    float* hB   = ws; ws += (size_t)N_NODES * NHID;
    float* hk   = ws; ws += (size_t)N_NODES * NHID;
    float* hv   = ws; ws += (size_t)N_NODES * NHID;
    float* qb_  = ws; ws += (size_t)N_NODES * NHID;
    float* agg  = ws; ws += (size_t)N_NODES * NHID;
    float* att  = ws; ws += (size_t)N_EDGES * HH;
    float* tab  = ws; ws += MAXT_ * NHID;
    float* proj = ws; ws += MAXT_ * NHID;
    float* RK   = ws; ws += MAXT_ * TT * NHID;
    float* RV   = ws; ws += MAXT_ * TT * NHID;
    int*   deg    = (int*)ws; ws += N_NODES;
    int*   rowptr = (int*)ws; ws += N_NODES + 1;
    int*   cursor = (int*)ws; ws += N_NODES;
    int*   elist  = (int*)ws; ws += N_EDGES;
    int*   cnt    = (int*)ws; ws += 4;
    int*   lists  = (int*)ws; ws += (size_t)TT * N_NODES;

    const int nodeBlocksX = (N_NODES + NPB - 1) / NPB;  // 3125
    dim3 nodeGrid(nodeBlocksX, TT);
    const int edgeBlocks = (N_EDGES * HH + 255) / 256;  // 15625
    const int eB = (N_EDGES + 255) / 256;

    // type bins + CSR build (inputs constant; rebuilt each call for capture safety)
    hipMemsetAsync(cnt, 0, 4 * sizeof(int), stream);
    hipMemsetAsync(deg, 0, N_NODES * sizeof(int), stream);
    k_bin<<<(N_NODES + 255) / 256, 256, 0, stream>>>(node_type, cnt, lists);
    k_deg<<<eB, 256, 0, stream>>>(tgt, deg);
    k_scan<<<1, 1024, 0, stream>>>(deg, rowptr);
    hipMemcpyAsync(cursor, rowptr, N_NODES * sizeof(int),
                   hipMemcpyDeviceToDevice, stream);
    k_fill<<<eB, 256, 0, stream>>>(tgt, cursor, elist);

    k_sin_table<<<(MAXT_ * 64 + 255) / 256, 256, 0, stream>>>(tab);
    k_adapter<<<nodeGrid, 128, 0, stream>>>(node_feature, cnt, lists, adapt_W, adapt_b, hA);

    for (int l = 0; l < NLAYER; ++l) {
        const float* hin = (l == 0) ? hA : hB;
        float* hout = (l == 0) ? hB : (float*)d_out;
        const float* kW_l = kW + (size_t)l * TT * NHID * NHID;
        const float* kb_l = kb + (size_t)l * TT * NHID;
        const float* qW_l = qW + (size_t)l * TT * NHID * NHID;
        const float* qb_l = qb + (size_t)l * TT * NHID;
        const float* vW_l = vW + (size_t)l * TT * NHID * NHID;
        const float* vb_l = vb + (size_t)l * TT * NHID;
        const float* aW_l = aW + (size_t)l * TT * NHID * NHID;
        const float* ab_l = ab + (size_t)l * TT * NHID;
        const float* ratt_l = rel_att + (size_t)l * RR * HH * DKH * DKH;
        const float* rmsg_l = rel_msg + (size_t)l * RR * HH * DKH * DKH;
        const float* rpri_l = rel_pri + (size_t)l * RR * HH;
        const float* skip_l = skip + (size_t)l * TT;
        const float* rteW_l = rteW + (size_t)l * NHID * NHID;
        const float* rteb_l = rteb + (size_t)l * NHID;

        k_rte_proj<<<MAXT_, 128, 0, stream>>>(tab, rteW_l, rteb_l, proj);
        dim3 rkvGrid(MAXT_, TT);
        k_rkv<<<rkvGrid, 128, 0, stream>>>(proj, kW_l, vW_l, RK, RV);
        k_node_lin<<<nodeGrid, 128, 0, stream>>>(hin, cnt, lists,
                                                 kW_l, kb_l, qW_l, qb_l, vW_l, vb_l,
                                                 hk, qb_, hv);
        k_att<<<edgeBlocks, 256, 0, stream>>>(hk, qb_, RK, src, tgt, edge_type, edge_time,
                                              node_type, ratt_l, rpri_l, att);
        k_csr<<<N_NODES, 128, 0, stream>>>(hv, RV, att, rowptr, elist, src,
                                           edge_type, edge_time, node_type, rmsg_l, agg);
        k_out<<<nodeGrid, 128, 0, stream>>>(agg, hin, cnt, lists, aW_l, ab_l, skip_l, hout);
    }
}

// Round 5
// 1279.700 us; speedup vs baseline: 6.5915x; 1.8726x over previous
//
#include <hip/hip_runtime.h>
#include <float.h>
#include <math.h>

#define N_NODES 50000
#define N_EDGES 500000
#define TT 3
#define RR 4
#define HH 8
#define NHID 128
#define NLAYER 2
#define DIN_ 166
#define MAXT_ 240
#define DKH 16
#define NPB 16

// -------------------- setup kernels --------------------

// Sinusoid RTE table, computed in f64 to match numpy, cast to f32.
__global__ void k_sin_table(float* __restrict__ tab) {
    int idx = blockIdx.x * blockDim.x + threadIdx.x;
    if (idx >= MAXT_ * 64) return;
    int p = idx / 64, i2 = idx % 64;
    const double c = -9.210340371976184 / 128.0;   // -ln(10000)/NH
    double div = exp((double)(2 * i2) * c);
    double a = (double)p * div;
    const double s128 = 0.08838834764831845;       // 1/sqrt(128)
    tab[p * NHID + 2 * i2]     = (float)(sin(a) * s128);
    tab[p * NHID + 2 * i2 + 1] = (float)(cos(a) * s128);
}

// Bin nodes by type (wave-aggregated atomics: 3 atomics per wave).
__global__ void k_bin(const int* __restrict__ ntype, int* __restrict__ cnt,
                      int* __restrict__ lists) {
    int n = blockIdx.x * 256 + threadIdx.x;
    int t = (n < N_NODES) ? ntype[n] : -1;
    int lane = threadIdx.x & 63;
    #pragma unroll
    for (int tt = 0; tt < TT; ++tt) {
        unsigned long long mask = __ballot(t == tt);
        if (mask) {
            int leader = (int)__ffsll(mask) - 1;
            int base = 0;
            if (lane == leader) base = atomicAdd(&cnt[tt], __popcll(mask));
            base = __shfl(base, leader);
            if (t == tt) {
                int rank = __popcll(mask & ((1ULL << lane) - 1ULL));
                lists[tt * N_NODES + base + rank] = n;
            }
        }
    }
}

// -------------------- CSR build (once; edge_index constant across layers) ---

__global__ void k_deg(const int* __restrict__ tgt, int* __restrict__ deg) {
    int e = blockIdx.x * 256 + threadIdx.x;
    if (e < N_EDGES) atomicAdd(&deg[tgt[e]], 1);
}

// single-block exclusive scan: rowptr[0]=0, rowptr[i+1]=sum deg[0..i]
__global__ void k_scan(const int* __restrict__ deg, int* __restrict__ rowptr) {
    __shared__ int wsum[16];
    __shared__ int carry_s;
    int tid = threadIdx.x;           // 1024
    int lane = tid & 63, wid = tid >> 6;
    if (tid == 0) { carry_s = 0; rowptr[0] = 0; }
    __syncthreads();
    for (int base = 0; base < N_NODES; base += 1024) {
        int idx = base + tid;
        int x = (idx < N_NODES) ? deg[idx] : 0;
        #pragma unroll
        for (int off = 1; off < 64; off <<= 1) {
            int y = __shfl_up(x, off, 64);
            if (lane >= off) x += y;
        }
        if (lane == 63) wsum[wid] = x;
        __syncthreads();
        if (wid == 0) {
            int w = (lane < 16) ? wsum[lane] : 0;
            #pragma unroll
            for (int off = 1; off < 16; off <<= 1) {
                int y = __shfl_up(w, off, 64);
                if (lane >= off) w += y;
            }
            if (lane < 16) wsum[lane] = w;
        }
        __syncthreads();
        int waveoff = (wid > 0) ? wsum[wid - 1] : 0;
        int incl = carry_s + waveoff + x;
        if (idx < N_NODES) rowptr[idx + 1] = incl;
        __syncthreads();
        if (tid == 1023) carry_s = incl;
        __syncthreads();
    }
}

__global__ void k_fill(const int* __restrict__ tgt, int* __restrict__ cursor,
                       int* __restrict__ elist) {
    int e = blockIdx.x * 256 + threadIdx.x;
    if (e >= N_EDGES) return;
    int g = tgt[e];
    int p = atomicAdd(&cursor[g], 1);
    elist[p] = e;
}

// -------------------- node-level linears (type-binned) --------------------

__global__ void k_adapter(const float* __restrict__ x, const int* __restrict__ cnt,
                          const int* __restrict__ lists,
                          const float* __restrict__ W, const float* __restrict__ b,
                          float* __restrict__ h) {
    int t = blockIdx.y;
    int c = cnt[t];
    int i0 = blockIdx.x * NPB;
    if (i0 >= c) return;
    int j = threadIdx.x;
    __shared__ float xs[NPB][DIN_];
    __shared__ int nidx[NPB];
    if (j < NPB) nidx[j] = (i0 + j < c) ? lists[t * N_NODES + i0 + j] : -1;
    __syncthreads();
    int nr[NPB];
    #pragma unroll
    for (int m = 0; m < NPB; ++m) nr[m] = nidx[m];
    #pragma unroll
    for (int m = 0; m < NPB; ++m) {
        int n = nr[m];
        for (int d = j; d < DIN_; d += 128)
            xs[m][d] = (n >= 0) ? x[(size_t)n * DIN_ + d] : 0.f;
    }
    __syncthreads();
    const float* Wt = W + (size_t)t * DIN_ * NHID;
    float bj = b[t * NHID + j];
    float acc[NPB];
    #pragma unroll
    for (int m = 0; m < NPB; ++m) acc[m] = bj;
    for (int d = 0; d < DIN_; ++d) {
        float w = Wt[d * NHID + j];
        #pragma unroll
        for (int m = 0; m < NPB; ++m) acc[m] = fmaf(xs[m][d], w, acc[m]);
    }
    #pragma unroll
    for (int m = 0; m < NPB; ++m) {
        int n = nr[m];
        if (n >= 0) h[(size_t)n * NHID + j] = tanhf(acc[m]);
    }
}

__global__ void k_node_lin(const float* __restrict__ h, const int* __restrict__ cnt,
                           const int* __restrict__ lists,
                           const float* __restrict__ Wk, const float* __restrict__ bk,
                           const float* __restrict__ Wq, const float* __restrict__ bq,
                           const float* __restrict__ Wv, const float* __restrict__ bv,
                           float* __restrict__ hk, float* __restrict__ q,
                           float* __restrict__ hv) {
    int t = blockIdx.y;
    int c = cnt[t];
    int i0 = blockIdx.x * NPB;
    if (i0 >= c) return;
    int j = threadIdx.x;
    __shared__ float hs[NPB][NHID];
    __shared__ int nidx[NPB];
    if (j < NPB) nidx[j] = (i0 + j < c) ? lists[t * N_NODES + i0 + j] : -1;
    __syncthreads();
    int nr[NPB];
    #pragma unroll
    for (int m = 0; m < NPB; ++m) nr[m] = nidx[m];
    #pragma unroll
    for (int m = 0; m < NPB; ++m)
        hs[m][j] = (nr[m] >= 0) ? h[(size_t)nr[m] * NHID + j] : 0.f;
    __syncthreads();
    const float* WkT = Wk + (size_t)t * NHID * NHID;
    const float* WqT = Wq + (size_t)t * NHID * NHID;
    const float* WvT = Wv + (size_t)t * NHID * NHID;
    float ak[NPB], aq[NPB], av[NPB];
    float bkj = bk[t * NHID + j], bqj = bq[t * NHID + j], bvj = bv[t * NHID + j];
    #pragma unroll
    for (int m = 0; m < NPB; ++m) { ak[m] = bkj; aq[m] = bqj; av[m] = bvj; }
    for (int i = 0; i < NHID; ++i) {
        float wk = WkT[i * NHID + j];
        float wq = WqT[i * NHID + j];
        float wv = WvT[i * NHID + j];
        #pragma unroll
        for (int m = 0; m < NPB; ++m) {
            float hi = hs[m][i];
            ak[m] = fmaf(hi, wk, ak[m]);
            aq[m] = fmaf(hi, wq, aq[m]);
            av[m] = fmaf(hi, wv, av[m]);
        }
    }
    #pragma unroll
    for (int m = 0; m < NPB; ++m) {
        int n = nr[m];
        if (n >= 0) {
            hk[(size_t)n * NHID + j] = ak[m];
            q [(size_t)n * NHID + j] = aq[m];
            hv[(size_t)n * NHID + j] = av[m];
        }
    }
}

__global__ void k_out(const float* __restrict__ agg, const float* __restrict__ hin,
                      const int* __restrict__ cnt, const int* __restrict__ lists,
                      const float* __restrict__ aW, const float* __restrict__ ab,
                      const float* __restrict__ skp, float* __restrict__ hout) {
    int t = blockIdx.y;
    int c = cnt[t];
    int i0 = blockIdx.x * NPB;
    if (i0 >= c) return;
    int j = threadIdx.x;
    __shared__ float gs[NPB][NHID];
    __shared__ int nidx[NPB];
    if (j < NPB) nidx[j] = (i0 + j < c) ? lists[t * N_NODES + i0 + j] : -1;
    __syncthreads();
    int nr[NPB];
    #pragma unroll
    for (int m = 0; m < NPB; ++m) nr[m] = nidx[m];
    #pragma unroll
    for (int m = 0; m < NPB; ++m) {
        int n = nr[m];
        float xv = (n >= 0) ? agg[(size_t)n * NHID + j] : 0.f;
        gs[m][j] = 0.5f * xv * (1.f + erff(xv * 0.7071067811865476f));
    }
    __syncthreads();
    const float* Wt = aW + (size_t)t * NHID * NHID;
    float bj = ab[t * NHID + j];
    float acc[NPB];
    #pragma unroll
    for (int m = 0; m < NPB; ++m) acc[m] = bj;
    for (int i = 0; i < NHID; ++i) {
        float w = Wt[i * NHID + j];
        #pragma unroll
        for (int m = 0; m < NPB; ++m) acc[m] = fmaf(gs[m][i], w, acc[m]);
    }
    float alpha = 1.f / (1.f + expf(-skp[t]));
    #pragma unroll
    for (int m = 0; m < NPB; ++m) {
        int n = nr[m];
        if (n >= 0)
            hout[(size_t)n * NHID + j] =
                acc[m] * alpha + hin[(size_t)n * NHID + j] * (1.f - alpha);
    }
}

// -------------------- tiny RTE projections --------------------

__global__ void k_rte_proj(const float* __restrict__ tab, const float* __restrict__ rteW,
                           const float* __restrict__ rteb, float* __restrict__ proj) {
    int p = blockIdx.x;
    int j = threadIdx.x;
    __shared__ float ts[NHID];
    ts[j] = tab[p * NHID + j];
    __syncthreads();
    float acc = rteb[j];
    for (int i = 0; i < NHID; ++i) acc = fmaf(ts[i], rteW[i * NHID + j], acc);
    proj[p * NHID + j] = acc;
}

__global__ void k_rkv(const float* __restrict__ proj, const float* __restrict__ kW,
                      const float* __restrict__ vW, float* __restrict__ RK,
                      float* __restrict__ RV) {
    int p = blockIdx.x, t = blockIdx.y;
    int j = threadIdx.x;
    __shared__ float ps[NHID];
    ps[j] = proj[p * NHID + j];
    __syncthreads();
    const float* Wk = kW + (size_t)t * NHID * NHID;
    const float* Wv = vW + (size_t)t * NHID * NHID;
    float ak = 0.f, av = 0.f;
    for (int i = 0; i < NHID; ++i) {
        float pi = ps[i];
        ak = fmaf(pi, Wk[i * NHID + j], ak);
        av = fmaf(pi, Wv[i * NHID + j], av);
    }
    RK[((size_t)p * TT + t) * NHID + j] = ak;
    RV[((size_t)p * TT + t) * NHID + j] = av;
}

// -------------------- edge pass 1: attention scores --------------------

// att[e,h] = (q[tgt] . A_rh^T(hk[src]+RK)) * pri / 4  — plain coalesced write.
// LDS swizzle: off ^ rh → at fixed (d,f) the 32 distinct rh land in 32 banks.
__global__ __launch_bounds__(256) void k_att(
        const float* __restrict__ hk, const float* __restrict__ q,
        const float* __restrict__ RK,
        const int* __restrict__ src, const int* __restrict__ tgt,
        const int* __restrict__ etype, const int* __restrict__ etime,
        const int* __restrict__ ntype,
        const float* __restrict__ rel_att, const float* __restrict__ rel_pri,
        float* __restrict__ att) {
    __shared__ float As[RR * HH * 256];   // 32 KB, XOR-swizzled
    int tid = threadIdx.x;
    for (int i = tid; i < RR * HH * 256; i += 256) {
        int rh = i >> 8, off = i & 255;
        As[(rh << 8) | (off ^ rh)] = rel_att[i];
    }
    __syncthreads();
    int idx = blockIdx.x * 256 + tid;
    if (idx >= N_EDGES * HH) return;
    int e = idx >> 3, h = idx & 7;
    int s = src[e], g = tgt[e];
    int r = etype[e], tm = etime[e];
    int t = ntype[s];
    float kv[DKH];
    const float* hkp = hk + (size_t)s * NHID + h * DKH;
    const float* rkp = RK + ((size_t)tm * TT + t) * NHID + h * DKH;
    #pragma unroll
    for (int d = 0; d < DKH; ++d) kv[d] = hkp[d] + rkp[d];
    const float* qp = q + (size_t)g * NHID + h * DKH;
    int rh = r * HH + h;
    const float* A = As + (rh << 8);
    float acc = 0.f;
    #pragma unroll
    for (int f = 0; f < DKH; ++f) {
        float tmp = 0.f;
        #pragma unroll
        for (int d = 0; d < DKH; ++d) tmp = fmaf(kv[d], A[(d * 16 + f) ^ rh], tmp);
        acc = fmaf(tmp, qp[f], acc);
    }
    acc *= rel_pri[rh] * 0.25f;
    att[idx] = acc;
}

// -------------------- edge pass 2: CSR softmax + aggregate (no atomics) ----

// One 128-thread block per target node; thread j = h*16+f owns output dim j.
// M_r factored OUT of the edge loop: acc_r = sum_{e in r} w_e*vv_e (registers),
// then one 64-step shuffle-transform epilogue. No LDS at all -> high occupancy.
__global__ __launch_bounds__(128) void k_csr(
        const float* __restrict__ hv, const float* __restrict__ RV,
        const float* __restrict__ att,
        const int* __restrict__ rowptr, const int* __restrict__ elist,
        const int* __restrict__ src, const int* __restrict__ etype,
        const int* __restrict__ etime, const int* __restrict__ ntype,
        const float* __restrict__ rel_msg, float* __restrict__ agg) {
    int n = blockIdx.x;
    int tid = threadIdx.x;
    int h = tid >> 4, f = tid & 15;
    int beg = rowptr[n], end = rowptr[n + 1];

    // Phase A: online (max, sumexp) for head h; 16 lanes per head cooperate.
    float m = -FLT_MAX, ssum = 0.f;
    for (int k = beg + f; k < end; k += 16) {
        int e = elist[k];
        float a = att[(size_t)e * HH + h];
        if (a > m) { ssum *= expf(m - a); m = a; }
        ssum += expf(a - m);
    }
    #pragma unroll
    for (int mask = 1; mask <= 8; mask <<= 1) {
        float om = __shfl_xor(m, mask, 64);
        float os = __shfl_xor(ssum, mask, 64);
        float nm = fmaxf(m, om);
        ssum = ssum * expf(m - nm) + os * expf(om - nm);
        m = nm;
    }
    float rden = 1.f / fmaxf(ssum, 1e-9f);

    // Phase B: per-relation weighted sums at dim tid (registers, no matrix).
    float a0 = 0.f, a1 = 0.f, a2 = 0.f, a3 = 0.f;
    #pragma unroll 2
    for (int k = beg; k < end; ++k) {
        int e = elist[k];
        int s = src[e], r = etype[e], tm = etime[e];
        int t = ntype[s];
        float vvt = hv[(size_t)s * NHID + tid] + RV[((size_t)tm * TT + t) * NHID + tid];
        float w = expf(att[(size_t)e * HH + h] - m) * rden;
        float wv = w * vvt;
        a0 += (r == 0) ? wv : 0.f;
        a1 += (r == 1) ? wv : 0.f;
        a2 += (r == 2) ? wv : 0.f;
        a3 += (r == 3) ? wv : 0.f;
    }

    // Epilogue: agg[n][h*16+f] = sum_r sum_d M_r[h][d][f] * acc_r[dim h*16+d].
    // M read straight from global (128 KB, L2-hot); once per node, not per edge.
    int lanebase = tid & 48;
    float out = 0.f;
    #pragma unroll
    for (int r = 0; r < RR; ++r) {
        float ar = (r == 0) ? a0 : (r == 1) ? a1 : (r == 2) ? a2 : a3;
        const float* M = rel_msg + ((r * HH + h) << 8) + f;
        #pragma unroll
        for (int d = 0; d < DKH; ++d) {
            float vd = __shfl(ar, lanebase + d, 64);
            out = fmaf(vd, M[d * 16], out);
        }
    }
    agg[(size_t)n * NHID + tid] = out;
}

// -------------------- launch --------------------

extern "C" void kernel_launch(void* const* d_in, const int* in_sizes, int n_in,
                              void* d_out, int out_size, void* d_ws, size_t ws_size,
                              hipStream_t stream) {
    const float* node_feature = (const float*)d_in[0];
    const int*   node_type    = (const int*)d_in[1];
    const int*   edge_time    = (const int*)d_in[2];
    const int*   edge_index   = (const int*)d_in[3];
    const int*   edge_type    = (const int*)d_in[4];
    const float* adapt_W = (const float*)d_in[5];
    const float* adapt_b = (const float*)d_in[6];
    const float* kW = (const float*)d_in[7];
    const float* kb = (const float*)d_in[8];
    const float* qW = (const float*)d_in[9];
    const float* qb = (const float*)d_in[10];
    const float* vW = (const float*)d_in[11];
    const float* vb = (const float*)d_in[12];
    const float* aW = (const float*)d_in[13];
    const float* ab = (const float*)d_in[14];
    const float* rel_att = (const float*)d_in[15];
    const float* rel_msg = (const float*)d_in[16];
    const float* rel_pri = (const float*)d_in[17];
    const float* skip = (const float*)d_in[18];
    const float* rteW = (const float*)d_in[19];
    const float* rteb = (const float*)d_in[20];

    const int* src = edge_index;             // edge_index[0][:]
    const int* tgt = edge_index + N_EDGES;   // edge_index[1][:]

    float* ws = (float*)d_ws;
    float* hA   = ws; ws += (size_t)N_NODES * NHID;
    float* hB   = ws; ws += (size_t)N_NODES * NHID;
    float* hk   = ws; ws += (size_t)N_NODES * NHID;
    float* hv   = ws; ws += (size_t)N_NODES * NHID;
    float* qb_  = ws; ws += (size_t)N_NODES * NHID;
    float* agg  = ws; ws += (size_t)N_NODES * NHID;
    float* att  = ws; ws += (size_t)N_EDGES * HH;
    float* tab  = ws; ws += MAXT_ * NHID;
    float* proj = ws; ws += MAXT_ * NHID;
    float* RK   = ws; ws += MAXT_ * TT * NHID;
    float* RV   = ws; ws += MAXT_ * TT * NHID;
    int*   deg    = (int*)ws; ws += N_NODES;
    int*   rowptr = (int*)ws; ws += N_NODES + 1;
    int*   cursor = (int*)ws; ws += N_NODES;
    int*   elist  = (int*)ws; ws += N_EDGES;
    int*   cnt    = (int*)ws; ws += 4;
    int*   lists  = (int*)ws; ws += (size_t)TT * N_NODES;

    const int nodeBlocksX = (N_NODES + NPB - 1) / NPB;  // 3125
    dim3 nodeGrid(nodeBlocksX, TT);
    const int edgeBlocks = (N_EDGES * HH + 255) / 256;  // 15625
    const int eB = (N_EDGES + 255) / 256;

    // type bins + CSR build (inputs constant; rebuilt each call for capture safety)
    hipMemsetAsync(cnt, 0, 4 * sizeof(int), stream);
    hipMemsetAsync(deg, 0, N_NODES * sizeof(int), stream);
    k_bin<<<(N_NODES + 255) / 256, 256, 0, stream>>>(node_type, cnt, lists);
    k_deg<<<eB, 256, 0, stream>>>(tgt, deg);
    k_scan<<<1, 1024, 0, stream>>>(deg, rowptr);
    hipMemcpyAsync(cursor, rowptr, N_NODES * sizeof(int),
                   hipMemcpyDeviceToDevice, stream);
    k_fill<<<eB, 256, 0, stream>>>(tgt, cursor, elist);

    k_sin_table<<<(MAXT_ * 64 + 255) / 256, 256, 0, stream>>>(tab);
    k_adapter<<<nodeGrid, 128, 0, stream>>>(node_feature, cnt, lists, adapt_W, adapt_b, hA);

    for (int l = 0; l < NLAYER; ++l) {
        const float* hin = (l == 0) ? hA : hB;
        float* hout = (l == 0) ? hB : (float*)d_out;
        const float* kW_l = kW + (size_t)l * TT * NHID * NHID;
        const float* kb_l = kb + (size_t)l * TT * NHID;
        const float* qW_l = qW + (size_t)l * TT * NHID * NHID;
        const float* qb_l = qb + (size_t)l * TT * NHID;
        const float* vW_l = vW + (size_t)l * TT * NHID * NHID;
        const float* vb_l = vb + (size_t)l * TT * NHID;
        const float* aW_l = aW + (size_t)l * TT * NHID * NHID;
        const float* ab_l = ab + (size_t)l * TT * NHID;
        const float* ratt_l = rel_att + (size_t)l * RR * HH * DKH * DKH;
        const float* rmsg_l = rel_msg + (size_t)l * RR * HH * DKH * DKH;
        const float* rpri_l = rel_pri + (size_t)l * RR * HH;
        const float* skip_l = skip + (size_t)l * TT;
        const float* rteW_l = rteW + (size_t)l * NHID * NHID;
        const float* rteb_l = rteb + (size_t)l * NHID;

        k_rte_proj<<<MAXT_, 128, 0, stream>>>(tab, rteW_l, rteb_l, proj);
        dim3 rkvGrid(MAXT_, TT);
        k_rkv<<<rkvGrid, 128, 0, stream>>>(proj, kW_l, vW_l, RK, RV);
        k_node_lin<<<nodeGrid, 128, 0, stream>>>(hin, cnt, lists,
                                                 kW_l, kb_l, qW_l, qb_l, vW_l, vb_l,
                                                 hk, qb_, hv);
        k_att<<<edgeBlocks, 256, 0, stream>>>(hk, qb_, RK, src, tgt, edge_type, edge_time,
                                              node_type, ratt_l, rpri_l, att);
        k_csr<<<N_NODES, 128, 0, stream>>>(hv, RV, att, rowptr, elist, src,
                                           edge_type, edge_time, node_type, rmsg_l, agg);
        k_out<<<nodeGrid, 128, 0, stream>>>(agg, hin, cnt, lists, aW_l, ab_l, skip_l, hout);
    }
}

// Round 7
// 1253.835 us; speedup vs baseline: 6.7275x; 1.0206x over previous
//
#include <hip/hip_runtime.h>
#include <float.h>
#include <math.h>

#define N_NODES 50000
#define N_EDGES 500000
#define TT 3
#define RR 4
#define HH 8
#define NHID 128
#define NLAYER 2
#define DIN_ 166
#define MAXT_ 240
#define DKH 16
#define NPB 16

// -------------------- setup kernels --------------------

// Sinusoid RTE table, computed in f64 to match numpy, cast to f32.
__global__ void k_sin_table(float* __restrict__ tab) {
    int idx = blockIdx.x * blockDim.x + threadIdx.x;
    if (idx >= MAXT_ * 64) return;
    int p = idx / 64, i2 = idx % 64;
    const double c = -9.210340371976184 / 128.0;   // -ln(10000)/NH
    double div = exp((double)(2 * i2) * c);
    double a = (double)p * div;
    const double s128 = 0.08838834764831845;       // 1/sqrt(128)
    tab[p * NHID + 2 * i2]     = (float)(sin(a) * s128);
    tab[p * NHID + 2 * i2 + 1] = (float)(cos(a) * s128);
}

// Bin nodes by type (wave-aggregated atomics: 3 atomics per wave).
__global__ void k_bin(const int* __restrict__ ntype, int* __restrict__ cnt,
                      int* __restrict__ lists) {
    int n = blockIdx.x * 256 + threadIdx.x;
    int t = (n < N_NODES) ? ntype[n] : -1;
    int lane = threadIdx.x & 63;
    #pragma unroll
    for (int tt = 0; tt < TT; ++tt) {
        unsigned long long mask = __ballot(t == tt);
        if (mask) {
            int leader = (int)__ffsll(mask) - 1;
            int base = 0;
            if (lane == leader) base = atomicAdd(&cnt[tt], __popcll(mask));
            base = __shfl(base, leader);
            if (t == tt) {
                int rank = __popcll(mask & ((1ULL << lane) - 1ULL));
                lists[tt * N_NODES + base + rank] = n;
            }
        }
    }
}

// -------------------- CSR build (once; edge_index constant across layers) ---

__global__ void k_deg(const int* __restrict__ tgt, int* __restrict__ deg) {
    int e = blockIdx.x * 256 + threadIdx.x;
    if (e < N_EDGES) atomicAdd(&deg[tgt[e]], 1);
}

// single-block exclusive scan: rowptr[0]=0, rowptr[i+1]=sum deg[0..i]
__global__ void k_scan(const int* __restrict__ deg, int* __restrict__ rowptr) {
    __shared__ int wsum[16];
    __shared__ int carry_s;
    int tid = threadIdx.x;           // 1024
    int lane = tid & 63, wid = tid >> 6;
    if (tid == 0) { carry_s = 0; rowptr[0] = 0; }
    __syncthreads();
    for (int base = 0; base < N_NODES; base += 1024) {
        int idx = base + tid;
        int x = (idx < N_NODES) ? deg[idx] : 0;
        #pragma unroll
        for (int off = 1; off < 64; off <<= 1) {
            int y = __shfl_up(x, off, 64);
            if (lane >= off) x += y;
        }
        if (lane == 63) wsum[wid] = x;
        __syncthreads();
        if (wid == 0) {
            int w = (lane < 16) ? wsum[lane] : 0;
            #pragma unroll
            for (int off = 1; off < 16; off <<= 1) {
                int y = __shfl_up(w, off, 64);
                if (lane >= off) w += y;
            }
            if (lane < 16) wsum[lane] = w;
        }
        __syncthreads();
        int waveoff = (wid > 0) ? wsum[wid - 1] : 0;
        int incl = carry_s + waveoff + x;
        if (idx < N_NODES) rowptr[idx + 1] = incl;
        __syncthreads();
        if (tid == 1023) carry_s = incl;
        __syncthreads();
    }
}

// Fill CSR-ordered edge attribute arrays (replaces elist indirection):
// sE = src node, gE = target node, attr = (etype<<12)|(etime*TT + ntype[src]).
__global__ void k_fill(const int* __restrict__ src, const int* __restrict__ tgt,
                       const int* __restrict__ etype, const int* __restrict__ etime,
                       const int* __restrict__ ntype, int* __restrict__ cursor,
                       int* __restrict__ sE, int* __restrict__ attr,
                       int* __restrict__ gE) {
    int e = blockIdx.x * 256 + threadIdx.x;
    if (e >= N_EDGES) return;
    int g = tgt[e];
    int s = src[e];
    int r = etype[e];
    int tm = etime[e];
    int t = ntype[s];
    int p = atomicAdd(&cursor[g], 1);
    sE[p] = s;
    attr[p] = (r << 12) | (tm * TT + t);
    gE[p] = g;
}

// -------------------- node-level linears (type-binned) --------------------

__global__ void k_adapter(const float* __restrict__ x, const int* __restrict__ cnt,
                          const int* __restrict__ lists,
                          const float* __restrict__ W, const float* __restrict__ b,
                          float* __restrict__ h) {
    int t = blockIdx.y;
    int c = cnt[t];
    int i0 = blockIdx.x * NPB;
    if (i0 >= c) return;
    int j = threadIdx.x;
    __shared__ float xs[NPB][DIN_];
    __shared__ int nidx[NPB];
    if (j < NPB) nidx[j] = (i0 + j < c) ? lists[t * N_NODES + i0 + j] : -1;
    __syncthreads();
    int nr[NPB];
    #pragma unroll
    for (int m = 0; m < NPB; ++m) nr[m] = nidx[m];
    #pragma unroll
    for (int m = 0; m < NPB; ++m) {
        int n = nr[m];
        for (int d = j; d < DIN_; d += 128)
            xs[m][d] = (n >= 0) ? x[(size_t)n * DIN_ + d] : 0.f;
    }
    __syncthreads();
    const float* Wt = W + (size_t)t * DIN_ * NHID;
    float bj = b[t * NHID + j];
    float acc[NPB];
    #pragma unroll
    for (int m = 0; m < NPB; ++m) acc[m] = bj;
    for (int d = 0; d < DIN_; ++d) {
        float w = Wt[d * NHID + j];
        #pragma unroll
        for (int m = 0; m < NPB; ++m) acc[m] = fmaf(xs[m][d], w, acc[m]);
    }
    #pragma unroll
    for (int m = 0; m < NPB; ++m) {
        int n = nr[m];
        if (n >= 0) h[(size_t)n * NHID + j] = tanhf(acc[m]);
    }
}

__global__ void k_node_lin(const float* __restrict__ h, const int* __restrict__ cnt,
                           const int* __restrict__ lists,
                           const float* __restrict__ Wk, const float* __restrict__ bk,
                           const float* __restrict__ Wq, const float* __restrict__ bq,
                           const float* __restrict__ Wv, const float* __restrict__ bv,
                           float* __restrict__ hk, float* __restrict__ q,
                           float* __restrict__ hv) {
    int t = blockIdx.y;
    int c = cnt[t];
    int i0 = blockIdx.x * NPB;
    if (i0 >= c) return;
    int j = threadIdx.x;
    __shared__ float hs[NPB][NHID];
    __shared__ int nidx[NPB];
    if (j < NPB) nidx[j] = (i0 + j < c) ? lists[t * N_NODES + i0 + j] : -1;
    __syncthreads();
    int nr[NPB];
    #pragma unroll
    for (int m = 0; m < NPB; ++m) nr[m] = nidx[m];
    #pragma unroll
    for (int m = 0; m < NPB; ++m)
        hs[m][j] = (nr[m] >= 0) ? h[(size_t)nr[m] * NHID + j] : 0.f;
    __syncthreads();
    const float* WkT = Wk + (size_t)t * NHID * NHID;
    const float* WqT = Wq + (size_t)t * NHID * NHID;
    const float* WvT = Wv + (size_t)t * NHID * NHID;
    float ak[NPB], aq[NPB], av[NPB];
    float bkj = bk[t * NHID + j], bqj = bq[t * NHID + j], bvj = bv[t * NHID + j];
    #pragma unroll
    for (int m = 0; m < NPB; ++m) { ak[m] = bkj; aq[m] = bqj; av[m] = bvj; }
    for (int i = 0; i < NHID; ++i) {
        float wk = WkT[i * NHID + j];
        float wq = WqT[i * NHID + j];
        float wv = WvT[i * NHID + j];
        #pragma unroll
        for (int m = 0; m < NPB; ++m) {
            float hi = hs[m][i];
            ak[m] = fmaf(hi, wk, ak[m]);
            aq[m] = fmaf(hi, wq, aq[m]);
            av[m] = fmaf(hi, wv, av[m]);
        }
    }
    #pragma unroll
    for (int m = 0; m < NPB; ++m) {
        int n = nr[m];
        if (n >= 0) {
            hk[(size_t)n * NHID + j] = ak[m];
            q [(size_t)n * NHID + j] = aq[m];
            hv[(size_t)n * NHID + j] = av[m];
        }
    }
}

__global__ void k_out(const float* __restrict__ agg, const float* __restrict__ hin,
                      const int* __restrict__ cnt, const int* __restrict__ lists,
                      const float* __restrict__ aW, const float* __restrict__ ab,
                      const float* __restrict__ skp, float* __restrict__ hout) {
    int t = blockIdx.y;
    int c = cnt[t];
    int i0 = blockIdx.x * NPB;
    if (i0 >= c) return;
    int j = threadIdx.x;
    __shared__ float gs[NPB][NHID];
    __shared__ int nidx[NPB];
    if (j < NPB) nidx[j] = (i0 + j < c) ? lists[t * N_NODES + i0 + j] : -1;
    __syncthreads();
    int nr[NPB];
    #pragma unroll
    for (int m = 0; m < NPB; ++m) nr[m] = nidx[m];
    #pragma unroll
    for (int m = 0; m < NPB; ++m) {
        int n = nr[m];
        float xv = (n >= 0) ? agg[(size_t)n * NHID + j] : 0.f;
        gs[m][j] = 0.5f * xv * (1.f + erff(xv * 0.7071067811865476f));
    }
    __syncthreads();
    const float* Wt = aW + (size_t)t * NHID * NHID;
    float bj = ab[t * NHID + j];
    float acc[NPB];
    #pragma unroll
    for (int m = 0; m < NPB; ++m) acc[m] = bj;
    for (int i = 0; i < NHID; ++i) {
        float w = Wt[i * NHID + j];
        #pragma unroll
        for (int m = 0; m < NPB; ++m) acc[m] = fmaf(gs[m][i], w, acc[m]);
    }
    float alpha = 1.f / (1.f + expf(-skp[t]));
    #pragma unroll
    for (int m = 0; m < NPB; ++m) {
        int n = nr[m];
        if (n >= 0)
            hout[(size_t)n * NHID + j] =
                acc[m] * alpha + hin[(size_t)n * NHID + j] * (1.f - alpha);
    }
}

// -------------------- tiny RTE projections --------------------

__global__ void k_rte_proj(const float* __restrict__ tab, const float* __restrict__ rteW,
                           const float* __restrict__ rteb, float* __restrict__ proj) {
    int p = blockIdx.x;
    int j = threadIdx.x;
    __shared__ float ts[NHID];
    ts[j] = tab[p * NHID + j];
    __syncthreads();
    float acc = rteb[j];
    for (int i = 0; i < NHID; ++i) acc = fmaf(ts[i], rteW[i * NHID + j], acc);
    proj[p * NHID + j] = acc;
}

__global__ void k_rkv(const float* __restrict__ proj, const float* __restrict__ kW,
                      const float* __restrict__ vW, float* __restrict__ RK,
                      float* __restrict__ RV) {
    int p = blockIdx.x, t = blockIdx.y;
    int j = threadIdx.x;
    __shared__ float ps[NHID];
    ps[j] = proj[p * NHID + j];
    __syncthreads();
    const float* Wk = kW + (size_t)t * NHID * NHID;
    const float* Wv = vW + (size_t)t * NHID * NHID;
    float ak = 0.f, av = 0.f;
    for (int i = 0; i < NHID; ++i) {
        float pi = ps[i];
        ak = fmaf(pi, Wk[i * NHID + j], ak);
        av = fmaf(pi, Wv[i * NHID + j], av);
    }
    RK[((size_t)p * TT + t) * NHID + j] = ak;
    RV[((size_t)p * TT + t) * NHID + j] = av;
}

// -------------------- edge pass 1: attention scores (CSR order, h-plane) ---

// Grid (E/256, 8). att2[h*E + k] = (q[g] . A_rh^T(hk[s]+RK)) * pri / 4.
// CSR order: consecutive k share g -> q slice is L1-hot; writes coalesced.
// LDS: only this h's 4 A matrices (4 KB), r-swizzled -> conflict-free.
__global__ __launch_bounds__(256) void k_att(
        const float* __restrict__ hk, const float* __restrict__ q,
        const float* __restrict__ RK,
        const int* __restrict__ sE, const int* __restrict__ attr,
        const int* __restrict__ gE,
        const float* __restrict__ rel_att, const float* __restrict__ rel_pri,
        float* __restrict__ att2) {
    int h = blockIdx.y;
    __shared__ float As[RR * 256];   // 4 KB
    int tid = threadIdx.x;
    for (int i = tid; i < RR * 256; i += 256) {
        int r = i >> 8, off = i & 255;
        As[(r << 8) | (off ^ (r << 3))] = rel_att[((r * HH + h) << 8) | off];
    }
    __syncthreads();
    int k = blockIdx.x * 256 + tid;
    if (k >= N_EDGES) return;
    int s = sE[k];
    int a = attr[k];
    int r = a >> 12, row = a & 4095;
    int g = gE[k];
    const float4* hk4 = (const float4*)(hk + (size_t)s * NHID + h * DKH);
    const float4* rk4 = (const float4*)(RK + (size_t)row * NHID + h * DKH);
    const float4* q4  = (const float4*)(q  + (size_t)g * NHID + h * DKH);
    float kv[DKH], qp[DKH];
    #pragma unroll
    for (int v = 0; v < 4; ++v) {
        float4 hv4 = hk4[v], rv4 = rk4[v], qv4 = q4[v];
        kv[v*4+0] = hv4.x + rv4.x; kv[v*4+1] = hv4.y + rv4.y;
        kv[v*4+2] = hv4.z + rv4.z; kv[v*4+3] = hv4.w + rv4.w;
        qp[v*4+0] = qv4.x; qp[v*4+1] = qv4.y; qp[v*4+2] = qv4.z; qp[v*4+3] = qv4.w;
    }
    const float* A = As + (r << 8);
    int sw = r << 3;
    float acc = 0.f;
    #pragma unroll
    for (int f = 0; f < DKH; ++f) {
        float tmp = 0.f;
        #pragma unroll
        for (int d = 0; d < DKH; ++d) tmp = fmaf(kv[d], A[(d * 16 + f) ^ sw], tmp);
        acc = fmaf(tmp, qp[f], acc);
    }
    acc *= rel_pri[r * HH + h] * 0.25f;
    att2[(size_t)h * N_EDGES + k] = acc;
}

// -------------------- edge pass 2: CSR softmax + aggregate --------------------

// One 128-thread block per target node; thread j = h*16+f owns output dim j.
// loop1: pure fmax. loop2: single expf per (e,h), stores unnormalized ex
// in-place into att2. Phase B: broadcast-read ex, 4 predicated FMAs.
// rden folded into one epilogue multiply.
__global__ __launch_bounds__(128) void k_csr(
        const float* __restrict__ hv, const float* __restrict__ RV,
        float* __restrict__ att2,
        const int* __restrict__ rowptr, const int* __restrict__ sE,
        const int* __restrict__ attr,
        const float* __restrict__ rel_msg, float* __restrict__ agg) {
    int n = blockIdx.x;
    int tid = threadIdx.x;
    int h = tid >> 4, f = tid & 15;
    int beg = rowptr[n], end = rowptr[n + 1];
    float* ap = att2 + (size_t)h * N_EDGES;

    // loop1: segment max for head h (16 lanes cooperate).
    float m = -FLT_MAX;
    for (int k = beg + f; k < end; k += 16) m = fmaxf(m, ap[k]);
    #pragma unroll
    for (int mask = 1; mask <= 8; mask <<= 1)
        m = fmaxf(m, __shfl_xor(m, mask, 64));

    // loop2: ex = expf(a-m), store back, accumulate denominator.
    float ssum = 0.f;
    for (int k = beg + f; k < end; k += 16) {
        float ex = expf(ap[k] - m);
        ap[k] = ex;
        ssum += ex;
    }
    #pragma unroll
    for (int mask = 1; mask <= 8; mask <<= 1)
        ssum += __shfl_xor(ssum, mask, 64);
    float rden = 1.f / fmaxf(ssum, 1e-9f);
    __syncthreads();   // make loop2's global writes visible to all lanes

    // Phase B: per-relation unnormalized weighted sums at dim tid.
    float a0 = 0.f, a1 = 0.f, a2 = 0.f, a3 = 0.f;
    #pragma unroll 2
    for (int k = beg; k < end; ++k) {
        int s = sE[k];
        int a = attr[k];
        int r = a >> 12, row = a & 4095;
        float vvt = hv[(size_t)s * NHID + tid] + RV[(size_t)row * NHID + tid];
        float wv = ap[k] * vvt;
        a0 += (r == 0) ? wv : 0.f;
        a1 += (r == 1) ? wv : 0.f;
        a2 += (r == 2) ? wv : 0.f;
        a3 += (r == 3) ? wv : 0.f;
    }

    // Epilogue: agg[n][h*16+f] = rden * sum_r sum_d M_r[h][d][f] * a_r[h*16+d].
    int lanebase = tid & 48;
    float out = 0.f;
    #pragma unroll
    for (int r = 0; r < RR; ++r) {
        float ar = (r == 0) ? a0 : (r == 1) ? a1 : (r == 2) ? a2 : a3;
        const float* M = rel_msg + ((r * HH + h) << 8) + f;
        #pragma unroll
        for (int d = 0; d < DKH; ++d) {
            float vd = __shfl(ar, lanebase + d, 64);
            out = fmaf(vd, M[d * 16], out);
        }
    }
    agg[(size_t)n * NHID + tid] = out * rden;
}

// -------------------- launch --------------------

extern "C" void kernel_launch(void* const* d_in, const int* in_sizes, int n_in,
                              void* d_out, int out_size, void* d_ws, size_t ws_size,
                              hipStream_t stream) {
    const float* node_feature = (const float*)d_in[0];
    const int*   node_type    = (const int*)d_in[1];
    const int*   edge_time    = (const int*)d_in[2];
    const int*   edge_index   = (const int*)d_in[3];
    const int*   edge_type    = (const int*)d_in[4];
    const float* adapt_W = (const float*)d_in[5];
    const float* adapt_b = (const float*)d_in[6];
    const float* kW = (const float*)d_in[7];
    const float* kb = (const float*)d_in[8];
    const float* qW = (const float*)d_in[9];
    const float* qb = (const float*)d_in[10];
    const float* vW = (const float*)d_in[11];
    const float* vb = (const float*)d_in[12];
    const float* aW = (const float*)d_in[13];
    const float* ab = (const float*)d_in[14];
    const float* rel_att = (const float*)d_in[15];
    const float* rel_msg = (const float*)d_in[16];
    const float* rel_pri = (const float*)d_in[17];
    const float* skip = (const float*)d_in[18];
    const float* rteW = (const float*)d_in[19];
    const float* rteb = (const float*)d_in[20];

    const int* src = edge_index;             // edge_index[0][:]
    const int* tgt = edge_index + N_EDGES;   // edge_index[1][:]

    float* ws = (float*)d_ws;
    float* hA   = ws; ws += (size_t)N_NODES * NHID;
    float* hB   = ws; ws += (size_t)N_NODES * NHID;
    float* hk   = ws; ws += (size_t)N_NODES * NHID;
    float* hv   = ws; ws += (size_t)N_NODES * NHID;
    float* qb_  = ws; ws += (size_t)N_NODES * NHID;
    float* agg  = ws; ws += (size_t)N_NODES * NHID;
    float* att2 = ws; ws += (size_t)N_EDGES * HH;
    float* tab  = ws; ws += MAXT_ * NHID;
    float* proj = ws; ws += MAXT_ * NHID;
    float* RK   = ws; ws += MAXT_ * TT * NHID;
    float* RV   = ws; ws += MAXT_ * TT * NHID;
    int*   deg    = (int*)ws; ws += N_NODES;
    int*   rowptr = (int*)ws; ws += N_NODES + 1;
    int*   cursor = (int*)ws; ws += N_NODES;
    int*   sE     = (int*)ws; ws += N_EDGES;
    int*   attr   = (int*)ws; ws += N_EDGES;
    int*   gE     = (int*)ws; ws += N_EDGES;
    int*   cnt    = (int*)ws; ws += 4;
    int*   lists  = (int*)ws; ws += (size_t)TT * N_NODES;

    const int nodeBlocksX = (N_NODES + NPB - 1) / NPB;  // 3125
    dim3 nodeGrid(nodeBlocksX, TT);
    const int eB = (N_EDGES + 255) / 256;               // 1954
    dim3 attGrid(eB, HH);

    // type bins + CSR build (inputs constant; rebuilt each call for capture safety)
    hipMemsetAsync(cnt, 0, 4 * sizeof(int), stream);
    hipMemsetAsync(deg, 0, N_NODES * sizeof(int), stream);
    k_bin<<<(N_NODES + 255) / 256, 256, 0, stream>>>(node_type, cnt, lists);
    k_deg<<<eB, 256, 0, stream>>>(tgt, deg);
    k_scan<<<1, 1024, 0, stream>>>(deg, rowptr);
    hipMemcpyAsync(cursor, rowptr, N_NODES * sizeof(int),
                   hipMemcpyDeviceToDevice, stream);
    k_fill<<<eB, 256, 0, stream>>>(src, tgt, edge_type, edge_time, node_type,
                                   cursor, sE, attr, gE);

    k_sin_table<<<(MAXT_ * 64 + 255) / 256, 256, 0, stream>>>(tab);
    k_adapter<<<nodeGrid, 128, 0, stream>>>(node_feature, cnt, lists, adapt_W, adapt_b, hA);

    for (int l = 0; l < NLAYER; ++l) {
        const float* hin = (l == 0) ? hA : hB;
        float* hout = (l == 0) ? hB : (float*)d_out;
        const float* kW_l = kW + (size_t)l * TT * NHID * NHID;
        const float* kb_l = kb + (size_t)l * TT * NHID;
        const float* qW_l = qW + (size_t)l * TT * NHID * NHID;
        const float* qb_l = qb + (size_t)l * TT * NHID;
        const float* vW_l = vW + (size_t)l * TT * NHID * NHID;
        const float* vb_l = vb + (size_t)l * TT * NHID;
        const float* aW_l = aW + (size_t)l * TT * NHID * NHID;
        const float* ab_l = ab + (size_t)l * TT * NHID;
        const float* ratt_l = rel_att + (size_t)l * RR * HH * DKH * DKH;
        const float* rmsg_l = rel_msg + (size_t)l * RR * HH * DKH * DKH;
        const float* rpri_l = rel_pri + (size_t)l * RR * HH;
        const float* skip_l = skip + (size_t)l * TT;
        const float* rteW_l = rteW + (size_t)l * NHID * NHID;
        const float* rteb_l = rteb + (size_t)l * NHID;

        k_rte_proj<<<MAXT_, 128, 0, stream>>>(tab, rteW_l, rteb_l, proj);
        dim3 rkvGrid(MAXT_, TT);
        k_rkv<<<rkvGrid, 128, 0, stream>>>(proj, kW_l, vW_l, RK, RV);
        k_node_lin<<<nodeGrid, 128, 0, stream>>>(hin, cnt, lists,
                                                 kW_l, kb_l, qW_l, qb_l, vW_l, vb_l,
                                                 hk, qb_, hv);
        k_att<<<attGrid, 256, 0, stream>>>(hk, qb_, RK, sE, attr, gE,
                                           ratt_l, rpri_l, att2);
        k_csr<<<N_NODES, 128, 0, stream>>>(hv, RV, att2, rowptr, sE, attr,
                                           rmsg_l, agg);
        k_out<<<nodeGrid, 128, 0, stream>>>(agg, hin, cnt, lists, aW_l, ab_l, skip_l, hout);
    }
}

// Round 8
// 1138.574 us; speedup vs baseline: 7.4085x; 1.1012x over previous
//
#include <hip/hip_runtime.h>
#include <hip/hip_fp16.h>
#include <float.h>
#include <math.h>

#define N_NODES 50000
#define N_EDGES 500000
#define TT 3
#define RR 4
#define HH 8
#define NHID 128
#define NLAYER 2
#define DIN_ 166
#define MAXT_ 240
#define DKH 16
#define NPB 16

// -------------------- setup kernels --------------------

// Sinusoid RTE table, computed in f64 to match numpy, cast to f32.
__global__ void k_sin_table(float* __restrict__ tab) {
    int idx = blockIdx.x * blockDim.x + threadIdx.x;
    if (idx >= MAXT_ * 64) return;
    int p = idx / 64, i2 = idx % 64;
    const double c = -9.210340371976184 / 128.0;   // -ln(10000)/NH
    double div = exp((double)(2 * i2) * c);
    double a = (double)p * div;
    const double s128 = 0.08838834764831845;       // 1/sqrt(128)
    tab[p * NHID + 2 * i2]     = (float)(sin(a) * s128);
    tab[p * NHID + 2 * i2 + 1] = (float)(cos(a) * s128);
}

// Bin nodes by type (wave-aggregated atomics: 3 atomics per wave).
__global__ void k_bin(const int* __restrict__ ntype, int* __restrict__ cnt,
                      int* __restrict__ lists) {
    int n = blockIdx.x * 256 + threadIdx.x;
    int t = (n < N_NODES) ? ntype[n] : -1;
    int lane = threadIdx.x & 63;
    #pragma unroll
    for (int tt = 0; tt < TT; ++tt) {
        unsigned long long mask = __ballot(t == tt);
        if (mask) {
            int leader = (int)__ffsll(mask) - 1;
            int base = 0;
            if (lane == leader) base = atomicAdd(&cnt[tt], __popcll(mask));
            base = __shfl(base, leader);
            if (t == tt) {
                int rank = __popcll(mask & ((1ULL << lane) - 1ULL));
                lists[tt * N_NODES + base + rank] = n;
            }
        }
    }
}

// -------------------- CSR build (once; edge_index constant across layers) ---

__global__ void k_deg(const int* __restrict__ tgt, int* __restrict__ deg) {
    int e = blockIdx.x * 256 + threadIdx.x;
    if (e < N_EDGES) atomicAdd(&deg[tgt[e]], 1);
}

// single-block exclusive scan: rowptr[0]=0, rowptr[i+1]=sum deg[0..i]
__global__ void k_scan(const int* __restrict__ deg, int* __restrict__ rowptr) {
    __shared__ int wsum[16];
    __shared__ int carry_s;
    int tid = threadIdx.x;           // 1024
    int lane = tid & 63, wid = tid >> 6;
    if (tid == 0) { carry_s = 0; rowptr[0] = 0; }
    __syncthreads();
    for (int base = 0; base < N_NODES; base += 1024) {
        int idx = base + tid;
        int x = (idx < N_NODES) ? deg[idx] : 0;
        #pragma unroll
        for (int off = 1; off < 64; off <<= 1) {
            int y = __shfl_up(x, off, 64);
            if (lane >= off) x += y;
        }
        if (lane == 63) wsum[wid] = x;
        __syncthreads();
        if (wid == 0) {
            int w = (lane < 16) ? wsum[lane] : 0;
            #pragma unroll
            for (int off = 1; off < 16; off <<= 1) {
                int y = __shfl_up(w, off, 64);
                if (lane >= off) w += y;
            }
            if (lane < 16) wsum[lane] = w;
        }
        __syncthreads();
        int waveoff = (wid > 0) ? wsum[wid - 1] : 0;
        int incl = carry_s + waveoff + x;
        if (idx < N_NODES) rowptr[idx + 1] = incl;
        __syncthreads();
        if (tid == 1023) carry_s = incl;
        __syncthreads();
    }
}

// Fill CSR-ordered edge attribute arrays (replaces elist indirection):
// sE = src node, gE = target node, attr = (etype<<12)|(etime*TT + ntype[src]).
__global__ void k_fill(const int* __restrict__ src, const int* __restrict__ tgt,
                       const int* __restrict__ etype, const int* __restrict__ etime,
                       const int* __restrict__ ntype, int* __restrict__ cursor,
                       int* __restrict__ sE, int* __restrict__ attr,
                       int* __restrict__ gE) {
    int e = blockIdx.x * 256 + threadIdx.x;
    if (e >= N_EDGES) return;
    int g = tgt[e];
    int s = src[e];
    int r = etype[e];
    int tm = etime[e];
    int t = ntype[s];
    int p = atomicAdd(&cursor[g], 1);
    sE[p] = s;
    attr[p] = (r << 12) | (tm * TT + t);
    gE[p] = g;
}

// -------------------- node-level linears (type-binned) --------------------

__global__ void k_adapter(const float* __restrict__ x, const int* __restrict__ cnt,
                          const int* __restrict__ lists,
                          const float* __restrict__ W, const float* __restrict__ b,
                          float* __restrict__ h) {
    int t = blockIdx.y;
    int c = cnt[t];
    int i0 = blockIdx.x * NPB;
    if (i0 >= c) return;
    int j = threadIdx.x;
    __shared__ float xs[NPB][DIN_];
    __shared__ int nidx[NPB];
    if (j < NPB) nidx[j] = (i0 + j < c) ? lists[t * N_NODES + i0 + j] : -1;
    __syncthreads();
    int nr[NPB];
    #pragma unroll
    for (int m = 0; m < NPB; ++m) nr[m] = nidx[m];
    #pragma unroll
    for (int m = 0; m < NPB; ++m) {
        int n = nr[m];
        for (int d = j; d < DIN_; d += 128)
            xs[m][d] = (n >= 0) ? x[(size_t)n * DIN_ + d] : 0.f;
    }
    __syncthreads();
    const float* Wt = W + (size_t)t * DIN_ * NHID;
    float bj = b[t * NHID + j];
    float acc[NPB];
    #pragma unroll
    for (int m = 0; m < NPB; ++m) acc[m] = bj;
    for (int d = 0; d < DIN_; ++d) {
        float w = Wt[d * NHID + j];
        #pragma unroll
        for (int m = 0; m < NPB; ++m) acc[m] = fmaf(xs[m][d], w, acc[m]);
    }
    #pragma unroll
    for (int m = 0; m < NPB; ++m) {
        int n = nr[m];
        if (n >= 0) h[(size_t)n * NHID + j] = tanhf(acc[m]);
    }
}

// hk/q/hv written as fp16 (gather tables for the edge kernels).
__global__ void k_node_lin(const float* __restrict__ h, const int* __restrict__ cnt,
                           const int* __restrict__ lists,
                           const float* __restrict__ Wk, const float* __restrict__ bk,
                           const float* __restrict__ Wq, const float* __restrict__ bq,
                           const float* __restrict__ Wv, const float* __restrict__ bv,
                           __half* __restrict__ hk16, __half* __restrict__ q16,
                           __half* __restrict__ hv16) {
    int t = blockIdx.y;
    int c = cnt[t];
    int i0 = blockIdx.x * NPB;
    if (i0 >= c) return;
    int j = threadIdx.x;
    __shared__ float hs[NPB][NHID];
    __shared__ int nidx[NPB];
    if (j < NPB) nidx[j] = (i0 + j < c) ? lists[t * N_NODES + i0 + j] : -1;
    __syncthreads();
    int nr[NPB];
    #pragma unroll
    for (int m = 0; m < NPB; ++m) nr[m] = nidx[m];
    #pragma unroll
    for (int m = 0; m < NPB; ++m)
        hs[m][j] = (nr[m] >= 0) ? h[(size_t)nr[m] * NHID + j] : 0.f;
    __syncthreads();
    const float* WkT = Wk + (size_t)t * NHID * NHID;
    const float* WqT = Wq + (size_t)t * NHID * NHID;
    const float* WvT = Wv + (size_t)t * NHID * NHID;
    float ak[NPB], aq[NPB], av[NPB];
    float bkj = bk[t * NHID + j], bqj = bq[t * NHID + j], bvj = bv[t * NHID + j];
    #pragma unroll
    for (int m = 0; m < NPB; ++m) { ak[m] = bkj; aq[m] = bqj; av[m] = bvj; }
    for (int i = 0; i < NHID; ++i) {
        float wk = WkT[i * NHID + j];
        float wq = WqT[i * NHID + j];
        float wv = WvT[i * NHID + j];
        #pragma unroll
        for (int m = 0; m < NPB; ++m) {
            float hi = hs[m][i];
            ak[m] = fmaf(hi, wk, ak[m]);
            aq[m] = fmaf(hi, wq, aq[m]);
            av[m] = fmaf(hi, wv, av[m]);
        }
    }
    #pragma unroll
    for (int m = 0; m < NPB; ++m) {
        int n = nr[m];
        if (n >= 0) {
            hk16[(size_t)n * NHID + j] = __float2half(ak[m]);
            q16 [(size_t)n * NHID + j] = __float2half(aq[m]);
            hv16[(size_t)n * NHID + j] = __float2half(av[m]);
        }
    }
}

__global__ void k_out(const float* __restrict__ agg, const float* __restrict__ hin,
                      const int* __restrict__ cnt, const int* __restrict__ lists,
                      const float* __restrict__ aW, const float* __restrict__ ab,
                      const float* __restrict__ skp, float* __restrict__ hout) {
    int t = blockIdx.y;
    int c = cnt[t];
    int i0 = blockIdx.x * NPB;
    if (i0 >= c) return;
    int j = threadIdx.x;
    __shared__ float gs[NPB][NHID];
    __shared__ int nidx[NPB];
    if (j < NPB) nidx[j] = (i0 + j < c) ? lists[t * N_NODES + i0 + j] : -1;
    __syncthreads();
    int nr[NPB];
    #pragma unroll
    for (int m = 0; m < NPB; ++m) nr[m] = nidx[m];
    #pragma unroll
    for (int m = 0; m < NPB; ++m) {
        int n = nr[m];
        float xv = (n >= 0) ? agg[(size_t)n * NHID + j] : 0.f;
        gs[m][j] = 0.5f * xv * (1.f + erff(xv * 0.7071067811865476f));
    }
    __syncthreads();
    const float* Wt = aW + (size_t)t * NHID * NHID;
    float bj = ab[t * NHID + j];
    float acc[NPB];
    #pragma unroll
    for (int m = 0; m < NPB; ++m) acc[m] = bj;
    for (int i = 0; i < NHID; ++i) {
        float w = Wt[i * NHID + j];
        #pragma unroll
        for (int m = 0; m < NPB; ++m) acc[m] = fmaf(gs[m][i], w, acc[m]);
    }
    float alpha = 1.f / (1.f + expf(-skp[t]));
    #pragma unroll
    for (int m = 0; m < NPB; ++m) {
        int n = nr[m];
        if (n >= 0)
            hout[(size_t)n * NHID + j] =
                acc[m] * alpha + hin[(size_t)n * NHID + j] * (1.f - alpha);
    }
}

// -------------------- tiny RTE projections --------------------

__global__ void k_rte_proj(const float* __restrict__ tab, const float* __restrict__ rteW,
                           const float* __restrict__ rteb, float* __restrict__ proj) {
    int p = blockIdx.x;
    int j = threadIdx.x;
    __shared__ float ts[NHID];
    ts[j] = tab[p * NHID + j];
    __syncthreads();
    float acc = rteb[j];
    for (int i = 0; i < NHID; ++i) acc = fmaf(ts[i], rteW[i * NHID + j], acc);
    proj[p * NHID + j] = acc;
}

// RK written fp16 (k_att gather); RV stays fp32 (k_csr adds in f32).
__global__ void k_rkv(const float* __restrict__ proj, const float* __restrict__ kW,
                      const float* __restrict__ vW, __half* __restrict__ RK16,
                      float* __restrict__ RV) {
    int p = blockIdx.x, t = blockIdx.y;
    int j = threadIdx.x;
    __shared__ float ps[NHID];
    ps[j] = proj[p * NHID + j];
    __syncthreads();
    const float* Wk = kW + (size_t)t * NHID * NHID;
    const float* Wv = vW + (size_t)t * NHID * NHID;
    float ak = 0.f, av = 0.f;
    for (int i = 0; i < NHID; ++i) {
        float pi = ps[i];
        ak = fmaf(pi, Wk[i * NHID + j], ak);
        av = fmaf(pi, Wv[i * NHID + j], av);
    }
    RK16[((size_t)p * TT + t) * NHID + j] = __float2half(ak);
    RV[((size_t)p * TT + t) * NHID + j] = av;
}

// -------------------- edge pass 1: attention scores --------------------

// idx = k*8+h: the 8 h-threads of an edge are ADJACENT LANES, so their 32B
// fp16 slice loads coalesce into one full-row fetch per edge (row fetched
// once, not 8x across h-planes). Scores in f32; fp16 only on gather tables.
__global__ __launch_bounds__(256) void k_att(
        const __half* __restrict__ hk16, const __half* __restrict__ q16,
        const __half* __restrict__ RK16,
        const int* __restrict__ sE, const int* __restrict__ attr,
        const int* __restrict__ gE,
        const float* __restrict__ rel_att, const float* __restrict__ rel_pri,
        float* __restrict__ att2) {
    __shared__ float As[RR * HH * 256];   // 32 KB, ^rh swizzle
    int tid = threadIdx.x;
    for (int i = tid; i < RR * HH * 256; i += 256) {
        int rh = i >> 8, off = i & 255;
        As[(rh << 8) | (off ^ rh)] = rel_att[i];
    }
    __syncthreads();
    int idx = blockIdx.x * 256 + tid;
    if (idx >= N_EDGES * HH) return;
    int k = idx >> 3, h = idx & 7;
    int s = sE[k];
    int a = attr[k];
    int r = a >> 12, row = a & 4095;
    int g = gE[k];
    const __half2* hk2 = (const __half2*)hk16 + (size_t)s * 64 + h * 8;
    const __half2* rk2 = (const __half2*)RK16 + (size_t)row * 64 + h * 8;
    const __half2* q2  = (const __half2*)q16 + (size_t)g * 64 + h * 8;
    float kv[DKH], qv[DKH];
    #pragma unroll
    for (int i = 0; i < 8; ++i) {
        float2 fa = __half22float2(hk2[i]);
        float2 fb = __half22float2(rk2[i]);
        float2 fc = __half22float2(q2[i]);
        kv[2*i]   = fa.x + fb.x;
        kv[2*i+1] = fa.y + fb.y;
        qv[2*i]   = fc.x;
        qv[2*i+1] = fc.y;
    }
    int rh = r * HH + h;
    const float* A = As + (rh << 8);
    float acc = 0.f;
    #pragma unroll
    for (int f = 0; f < DKH; ++f) {
        float tmp = 0.f;
        #pragma unroll
        for (int d = 0; d < DKH; ++d) tmp = fmaf(kv[d], A[(d * 16 + f) ^ rh], tmp);
        acc = fmaf(tmp, qv[f], acc);
    }
    acc *= rel_pri[rh] * 0.25f;
    att2[(size_t)h * N_EDGES + k] = acc;
}

// -------------------- edge pass 2: CSR softmax + aggregate --------------------

// One 128-thread block per target node; thread j = h*16+f owns output dim j.
__global__ __launch_bounds__(128) void k_csr(
        const __half* __restrict__ hv16, const float* __restrict__ RV,
        float* __restrict__ att2,
        const int* __restrict__ rowptr, const int* __restrict__ sE,
        const int* __restrict__ attr,
        const float* __restrict__ rel_msg, float* __restrict__ agg) {
    int n = blockIdx.x;
    int tid = threadIdx.x;
    int h = tid >> 4, f = tid & 15;
    int beg = rowptr[n], end = rowptr[n + 1];
    float* ap = att2 + (size_t)h * N_EDGES;

    // loop1: segment max for head h (16 lanes cooperate).
    float m = -FLT_MAX;
    for (int k = beg + f; k < end; k += 16) m = fmaxf(m, ap[k]);
    #pragma unroll
    for (int mask = 1; mask <= 8; mask <<= 1)
        m = fmaxf(m, __shfl_xor(m, mask, 64));

    // loop2: ex = expf(a-m), store back, accumulate denominator.
    float ssum = 0.f;
    for (int k = beg + f; k < end; k += 16) {
        float ex = expf(ap[k] - m);
        ap[k] = ex;
        ssum += ex;
    }
    #pragma unroll
    for (int mask = 1; mask <= 8; mask <<= 1)
        ssum += __shfl_xor(ssum, mask, 64);
    float rden = 1.f / fmaxf(ssum, 1e-9f);
    __syncthreads();   // make loop2's global writes visible to all lanes

    // Phase B: per-relation unnormalized weighted sums at dim tid.
    float a0 = 0.f, a1 = 0.f, a2 = 0.f, a3 = 0.f;
    #pragma unroll 2
    for (int k = beg; k < end; ++k) {
        int s = sE[k];
        int a = attr[k];
        int r = a >> 12, row = a & 4095;
        float vvt = __half2float(hv16[(size_t)s * NHID + tid])
                    + RV[(size_t)row * NHID + tid];
        float wv = ap[k] * vvt;
        a0 += (r == 0) ? wv : 0.f;
        a1 += (r == 1) ? wv : 0.f;
        a2 += (r == 2) ? wv : 0.f;
        a3 += (r == 3) ? wv : 0.f;
    }

    // Epilogue: agg[n][h*16+f] = rden * sum_r sum_d M_r[h][d][f] * a_r[h*16+d].
    int lanebase = tid & 48;
    float out = 0.f;
    #pragma unroll
    for (int r = 0; r < RR; ++r) {
        float ar = (r == 0) ? a0 : (r == 1) ? a1 : (r == 2) ? a2 : a3;
        const float* M = rel_msg + ((r * HH + h) << 8) + f;
        #pragma unroll
        for (int d = 0; d < DKH; ++d) {
            float vd = __shfl(ar, lanebase + d, 64);
            out = fmaf(vd, M[d * 16], out);
        }
    }
    agg[(size_t)n * NHID + tid] = out * rden;
}

// -------------------- launch --------------------

extern "C" void kernel_launch(void* const* d_in, const int* in_sizes, int n_in,
                              void* d_out, int out_size, void* d_ws, size_t ws_size,
                              hipStream_t stream) {
    const float* node_feature = (const float*)d_in[0];
    const int*   node_type    = (const int*)d_in[1];
    const int*   edge_time    = (const int*)d_in[2];
    const int*   edge_index   = (const int*)d_in[3];
    const int*   edge_type    = (const int*)d_in[4];
    const float* adapt_W = (const float*)d_in[5];
    const float* adapt_b = (const float*)d_in[6];
    const float* kW = (const float*)d_in[7];
    const float* kb = (const float*)d_in[8];
    const float* qW = (const float*)d_in[9];
    const float* qb = (const float*)d_in[10];
    const float* vW = (const float*)d_in[11];
    const float* vb = (const float*)d_in[12];
    const float* aW = (const float*)d_in[13];
    const float* ab = (const float*)d_in[14];
    const float* rel_att = (const float*)d_in[15];
    const float* rel_msg = (const float*)d_in[16];
    const float* rel_pri = (const float*)d_in[17];
    const float* skip = (const float*)d_in[18];
    const float* rteW = (const float*)d_in[19];
    const float* rteb = (const float*)d_in[20];

    const int* src = edge_index;             // edge_index[0][:]
    const int* tgt = edge_index + N_EDGES;   // edge_index[1][:]

    float* ws = (float*)d_ws;
    float* hA   = ws; ws += (size_t)N_NODES * NHID;
    float* hB   = ws; ws += (size_t)N_NODES * NHID;
    float* agg  = ws; ws += (size_t)N_NODES * NHID;
    float* att2 = ws; ws += (size_t)N_EDGES * HH;
    float* tab  = ws; ws += MAXT_ * NHID;
    float* proj = ws; ws += MAXT_ * NHID;
    float* RV   = ws; ws += MAXT_ * TT * NHID;
    __half* hk16 = (__half*)ws; ws += (size_t)N_NODES * NHID / 2;
    __half* q16  = (__half*)ws; ws += (size_t)N_NODES * NHID / 2;
    __half* hv16 = (__half*)ws; ws += (size_t)N_NODES * NHID / 2;
    __half* RK16 = (__half*)ws; ws += (size_t)MAXT_ * TT * NHID / 2;
    int*   deg    = (int*)ws; ws += N_NODES;
    int*   rowptr = (int*)ws; ws += N_NODES + 1;
    int*   cursor = (int*)ws; ws += N_NODES;
    int*   sE     = (int*)ws; ws += N_EDGES;
    int*   attr   = (int*)ws; ws += N_EDGES;
    int*   gE     = (int*)ws; ws += N_EDGES;
    int*   cnt    = (int*)ws; ws += 4;
    int*   lists  = (int*)ws; ws += (size_t)TT * N_NODES;

    const int nodeBlocksX = (N_NODES + NPB - 1) / NPB;  // 3125
    dim3 nodeGrid(nodeBlocksX, TT);
    const int eB = (N_EDGES + 255) / 256;               // 1954
    const int edgeBlocks = (N_EDGES * HH + 255) / 256;  // 15625

    // type bins + CSR build (inputs constant; rebuilt each call for capture safety)
    hipMemsetAsync(cnt, 0, 4 * sizeof(int), stream);
    hipMemsetAsync(deg, 0, N_NODES * sizeof(int), stream);
    k_bin<<<(N_NODES + 255) / 256, 256, 0, stream>>>(node_type, cnt, lists);
    k_deg<<<eB, 256, 0, stream>>>(tgt, deg);
    k_scan<<<1, 1024, 0, stream>>>(deg, rowptr);
    hipMemcpyAsync(cursor, rowptr, N_NODES * sizeof(int),
                   hipMemcpyDeviceToDevice, stream);
    k_fill<<<eB, 256, 0, stream>>>(src, tgt, edge_type, edge_time, node_type,
                                   cursor, sE, attr, gE);

    k_sin_table<<<(MAXT_ * 64 + 255) / 256, 256, 0, stream>>>(tab);
    k_adapter<<<nodeGrid, 128, 0, stream>>>(node_feature, cnt, lists, adapt_W, adapt_b, hA);

    for (int l = 0; l < NLAYER; ++l) {
        const float* hin = (l == 0) ? hA : hB;
        float* hout = (l == 0) ? hB : (float*)d_out;
        const float* kW_l = kW + (size_t)l * TT * NHID * NHID;
        const float* kb_l = kb + (size_t)l * TT * NHID;
        const float* qW_l = qW + (size_t)l * TT * NHID * NHID;
        const float* qb_l = qb + (size_t)l * TT * NHID;
        const float* vW_l = vW + (size_t)l * TT * NHID * NHID;
        const float* vb_l = vb + (size_t)l * TT * NHID;
        const float* aW_l = aW + (size_t)l * TT * NHID * NHID;
        const float* ab_l = ab + (size_t)l * TT * NHID;
        const float* ratt_l = rel_att + (size_t)l * RR * HH * DKH * DKH;
        const float* rmsg_l = rel_msg + (size_t)l * RR * HH * DKH * DKH;
        const float* rpri_l = rel_pri + (size_t)l * RR * HH;
        const float* skip_l = skip + (size_t)l * TT;
        const float* rteW_l = rteW + (size_t)l * NHID * NHID;
        const float* rteb_l = rteb + (size_t)l * NHID;

        k_rte_proj<<<MAXT_, 128, 0, stream>>>(tab, rteW_l, rteb_l, proj);
        dim3 rkvGrid(MAXT_, TT);
        k_rkv<<<rkvGrid, 128, 0, stream>>>(proj, kW_l, vW_l, RK16, RV);
        k_node_lin<<<nodeGrid, 128, 0, stream>>>(hin, cnt, lists,
                                                 kW_l, kb_l, qW_l, qb_l, vW_l, vb_l,
                                                 hk16, q16, hv16);
        k_att<<<edgeBlocks, 256, 0, stream>>>(hk16, q16, RK16, sE, attr, gE,
                                              ratt_l, rpri_l, att2);
        k_csr<<<N_NODES, 128, 0, stream>>>(hv16, RV, att2, rowptr, sE, attr,
                                           rmsg_l, agg);
        k_out<<<nodeGrid, 128, 0, stream>>>(agg, hin, cnt, lists, aW_l, ab_l, skip_l, hout);
    }
}